// Round 9
// baseline (3364.622 us; speedup 1.0000x reference)
//
#include <hip/hip_runtime.h>
#include <hip/hip_bf16.h>

// ViT forward, MI355X. Round-3 m97-style gemm_bt + XCD-chunked bijective block
// remap (T1, m204) so A-strips and weight panels are XCD-L2-resident; fused
// flash attention; merged per-layer weight transpose; bf16 t1.

typedef unsigned short u16;
typedef __hip_bfloat16 bf16;
typedef __bf16 bf16x8 __attribute__((ext_vector_type(8)));
typedef float f32x4 __attribute__((ext_vector_type(4)));

typedef const __attribute__((address_space(1))) void* gas_ptr;
typedef __attribute__((address_space(3))) void* las_ptr;

#define TOKENS 577
#define TPAD   640
#define DMODEL 512
#define SM_SCALE 0.08838834764831845f   /* 128^-0.5 */

static __device__ __forceinline__ u16 f2b(float v) {
    bf16 t = __float2bfloat16(v);
    return *(u16*)&t;
}

// ---------------------------------------------------------------------------
// Round-3 GEMM + XCD-chunked remap: blocks renumbered so XCD k (dispatch
// round-robin orig%8) owns a contiguous band of linear ids = contiguous
// row-strips x all column blocks -> A-strip + B panel L2-resident per XCD.
// C[M,N] = A[M,K] @ Bt[N,K]^T (+bias)(+gelu).
// OUTMODE 0: plain. 1: patch-embed epilogue (row remap b*577+1+t, +pos).
// ---------------------------------------------------------------------------
template<int OUTMODE, bool GELU>
__global__ __launch_bounds__(256)
void gemm_bt(const u16* __restrict__ A, int lda,
             const u16* __restrict__ Bt, int ldb,
             float* __restrict__ Cf, bf16* __restrict__ Cb, int ldc,
             const float* __restrict__ bias, const float* __restrict__ pos,
             int K, int rows_valid)
{
    // m204 bijective XCD-chunk remap
    const int gx = gridDim.x;
    const int nwg = gx * gridDim.y;
    const int orig = blockIdx.y * gx + blockIdx.x;
    const int q = nwg >> 3, r = nwg & 7;
    const int xcd = orig & 7, jj0 = orig >> 3;
    const int nid = (xcd < r ? xcd * (q + 1) : r * (q + 1) + (xcd - r) * q) + jj0;
    const int bxr = nid % gx, byr = nid / gx;

    __shared__ u16 As[128 * 64];
    __shared__ u16 Bs[128 * 64];
    const int tid  = threadIdx.x;
    const int w    = tid >> 6;
    const int lane = tid & 63;
    const u16* Ab = A + (long)byr * 128 * lda;
    const u16* Bb = Bt + (long)bxr * 128 * ldb;
    const int srow = w * 8 + (lane >> 3);
    const int scol = (lane & 7) * 8;
    const int wr = w >> 1, wc = w & 1;
    const int lr = lane & 15, lg = lane >> 4;
    f32x4 acc[4][4] = {};

    for (int kt = 0; kt < K; kt += 64) {
#pragma unroll
        for (int i = 0; i < 4; ++i) {
            const u16* ag = Ab + (long)(i * 32 + srow) * lda + kt + scol;
            const u16* bg = Bb + (long)(i * 32 + srow) * ldb + kt + scol;
            __builtin_amdgcn_global_load_lds((gas_ptr)ag, (las_ptr)&As[(i * 32 + w * 8) * 64], 16, 0, 0);
            __builtin_amdgcn_global_load_lds((gas_ptr)bg, (las_ptr)&Bs[(i * 32 + w * 8) * 64], 16, 0, 0);
        }
        __syncthreads();
#pragma unroll
        for (int kk = 0; kk < 2; ++kk) {
            const int ko = kk * 32 + lg * 8;
            bf16x8 af[4], bv[4];
#pragma unroll
            for (int m = 0; m < 4; ++m)
                af[m] = *(const bf16x8*)&As[(wr * 64 + m * 16 + lr) * 64 + ko];
#pragma unroll
            for (int n = 0; n < 4; ++n)
                bv[n] = *(const bf16x8*)&Bs[(wc * 64 + n * 16 + lr) * 64 + ko];
#pragma unroll
            for (int m = 0; m < 4; ++m)
#pragma unroll
                for (int n = 0; n < 4; ++n)
                    acc[m][n] = __builtin_amdgcn_mfma_f32_16x16x32_bf16(af[m], bv[n], acc[m][n], 0, 0, 0);
        }
        __syncthreads();
    }

    const int cbase = bxr * 128 + wc * 64;
    const int rbase = byr * 128 + wr * 64;
#pragma unroll
    for (int n = 0; n < 4; ++n) {
        const int c = cbase + n * 16 + lr;
        const float bval = bias ? bias[c] : 0.0f;
#pragma unroll
        for (int m = 0; m < 4; ++m) {
#pragma unroll
            for (int j = 0; j < 4; ++j) {
                const int rr = rbase + m * 16 + lg * 4 + j;
                if (rr >= rows_valid) continue;
                float v = acc[m][n][j] + bval;
                if constexpr (GELU) v = 0.5f * v * (1.0f + erff(v * 0.70710678118654752f));
                long idx;
                if constexpr (OUTMODE == 1) {
                    const int pb = rr / 576, pt = rr - pb * 576;
                    v += pos[(long)(1 + pt) * DMODEL + c];
                    idx = (long)(pb * TOKENS + 1 + pt) * ldc + c;
                } else {
                    idx = (long)rr * ldc + c;
                }
                if (Cf) Cf[idx] = v;
                if (Cb) Cb[idx] = __float2bfloat16(v);
            }
        }
    }
}

// ---------------------------------------------------------------------------
// Fused flash attention (round-3 verified). Grid: (5 q-tiles, NP pairs).
// qkv layout (permuted): [row][ kk*512 + h*128 + d ], row = b*577 + t (+pad).
// ---------------------------------------------------------------------------
__global__ __launch_bounds__(256, 2)
void attn_flash(const u16* __restrict__ qkv, const u16* __restrict__ vhT,
                bf16* __restrict__ ob)
{
    __shared__ u16 ldsA[128 * 128];
    __shared__ u16 ldsB[128 * 128];
    const int tid = threadIdx.x;
    const int w = tid >> 6, lane = tid & 63;
    const int lr = lane & 15, lg = lane >> 4;
    const int pair = blockIdx.y;
    const int b = pair >> 2, h = pair & 3;
    const int q0 = blockIdx.x * 128;
    const long rowbase = (long)b * TOKENS;

    bf16x8 qf[2][4];
#pragma unroll
    for (int m = 0; m < 2; ++m)
#pragma unroll
        for (int kf = 0; kf < 4; ++kf) {
            const long r = rowbase + q0 + w * 32 + m * 16 + lr;
            qf[m][kf] = *(const bf16x8*)&qkv[r * 1536 + h * 128 + kf * 32 + lg * 8];
        }

    float mrun[2][4], lrun[2][4];
#pragma unroll
    for (int m = 0; m < 2; ++m)
#pragma unroll
        for (int j = 0; j < 4; ++j) { mrun[m][j] = -1e30f; lrun[m][j] = 0.f; }
    f32x4 oacc[2][8] = {};

    for (int kv0 = 0; kv0 < TPAD; kv0 += 128) {
        {
            const u16* kg = qkv + (rowbase + kv0) * 1536 + 512 + h * 128;
            const u16* vg = vhT + ((long)pair * 128) * TPAD + kv0;
#pragma unroll
            for (int p = 0; p < 8; ++p) {
                const int i = p * 16 + w * 4 + lg;
                __builtin_amdgcn_global_load_lds((gas_ptr)(kg + (long)i * 1536 + lr * 8),
                                                 (las_ptr)&ldsA[(p * 16 + w * 4) * 128], 16, 0, 0);
                __builtin_amdgcn_global_load_lds((gas_ptr)(vg + (long)i * TPAD + lr * 8),
                                                 (las_ptr)&ldsB[(p * 16 + w * 4) * 128], 16, 0, 0);
            }
        }
        __syncthreads();

        f32x4 s[2][8] = {};
#pragma unroll
        for (int kf = 0; kf < 4; ++kf) {
            bf16x8 bv[8];
#pragma unroll
            for (int n = 0; n < 8; ++n)
                bv[n] = *(const bf16x8*)&ldsA[(n * 16 + lr) * 128 + kf * 32 + lg * 8];
            __builtin_amdgcn_s_setprio(1);
#pragma unroll
            for (int m = 0; m < 2; ++m)
#pragma unroll
                for (int n = 0; n < 8; ++n)
                    s[m][n] = __builtin_amdgcn_mfma_f32_16x16x32_bf16(qf[m][kf], bv[n], s[m][n], 0, 0, 0);
            __builtin_amdgcn_s_setprio(0);
        }

        float sc[2][4];
#pragma unroll
        for (int m = 0; m < 2; ++m)
#pragma unroll
            for (int jj = 0; jj < 4; ++jj) {
                float mx = mrun[m][jj];
#pragma unroll
                for (int n = 0; n < 8; ++n) {
                    const int col = kv0 + n * 16 + lr;
                    float v = s[m][n][jj] * SM_SCALE;
                    v = (col < TOKENS) ? v : -1e30f;
                    s[m][n][jj] = v;
                    mx = fmaxf(mx, v);
                }
#pragma unroll
                for (int o = 1; o < 16; o <<= 1) mx = fmaxf(mx, __shfl_xor(mx, o));
                const float f = __expf(mrun[m][jj] - mx);
                sc[m][jj] = f;
                float sum = 0.f;
#pragma unroll
                for (int n = 0; n < 8; ++n) {
                    const float p = __expf(s[m][n][jj] - mx);
                    s[m][n][jj] = p;
                    sum += p;
                }
#pragma unroll
                for (int o = 1; o < 16; o <<= 1) sum += __shfl_xor(sum, o);
                lrun[m][jj] = lrun[m][jj] * f + sum;
                mrun[m][jj] = mx;
            }
#pragma unroll
        for (int m = 0; m < 2; ++m)
#pragma unroll
            for (int n = 0; n < 8; ++n)
#pragma unroll
                for (int jj = 0; jj < 4; ++jj) oacc[m][n][jj] *= sc[m][jj];

        __syncthreads();
#pragma unroll
        for (int m = 0; m < 2; ++m)
#pragma unroll
            for (int n = 0; n < 8; ++n)
#pragma unroll
                for (int jj = 0; jj < 4; ++jj)
                    ldsA[(w * 32 + m * 16 + lg * 4 + jj) * 128 + n * 16 + lr] = f2b(s[m][n][jj]);
        __syncthreads();

#pragma unroll
        for (int kf = 0; kf < 4; ++kf) {
            bf16x8 pa[2];
#pragma unroll
            for (int m = 0; m < 2; ++m)
                pa[m] = *(const bf16x8*)&ldsA[(w * 32 + m * 16 + lr) * 128 + kf * 32 + lg * 8];
            __builtin_amdgcn_s_setprio(1);
#pragma unroll
            for (int n = 0; n < 8; ++n) {
                const bf16x8 vb = *(const bf16x8*)&ldsB[(n * 16 + lr) * 128 + kf * 32 + lg * 8];
#pragma unroll
                for (int m = 0; m < 2; ++m)
                    oacc[m][n] = __builtin_amdgcn_mfma_f32_16x16x32_bf16(pa[m], vb, oacc[m][n], 0, 0, 0);
            }
            __builtin_amdgcn_s_setprio(0);
        }
        __syncthreads();
    }

#pragma unroll
    for (int m = 0; m < 2; ++m)
#pragma unroll
        for (int jj = 0; jj < 4; ++jj) {
            const float inv = 1.f / lrun[m][jj];
            const int q = q0 + w * 32 + m * 16 + lg * 4 + jj;
            if (q >= TOKENS) continue;
#pragma unroll
            for (int n = 0; n < 8; ++n)
                ob[(rowbase + q) * DMODEL + h * 128 + n * 16 + lr] =
                    __float2bfloat16(oacc[m][n][jj] * inv);
        }
}

// ---------------------------------------------------------------------------
// Weight transpose + f32->bf16:  WT[n][k] = bf16(W[k][n]).
// Single-weight variant (patch embed, once).
// ---------------------------------------------------------------------------
__global__ __launch_bounds__(256)
void wtrans(const float* __restrict__ W, bf16* __restrict__ WT, int K, int N)
{
    __shared__ float tile[32][33];
    const int n0 = blockIdx.x * 32, k0 = blockIdx.y * 32;
    const int tx = threadIdx.x & 31, ty = threadIdx.x >> 5;
#pragma unroll
    for (int i = 0; i < 4; ++i)
        tile[ty + i * 8][tx] = W[(long)(k0 + ty + i * 8) * N + n0 + tx];
    __syncthreads();
#pragma unroll
    for (int i = 0; i < 4; ++i)
        WT[(long)(n0 + ty + i * 8) * K + k0 + tx] = __float2bfloat16(tile[tx][ty + i * 8]);
}

// ---------------------------------------------------------------------------
// Merged per-layer weight transpose: all four weights in one launch.
// seg0 Wqkv (512x1536, QKV col perm), seg1 W0 (512x512), seg2 W1 (512x2048),
// seg3 W2 (2048x512). Grid = 768 + 256 + 1024 + 1024 = 3072 blocks.
// ---------------------------------------------------------------------------
__global__ __launch_bounds__(256)
void wtrans_all(const float* __restrict__ Wqkv, const float* __restrict__ W0,
                const float* __restrict__ W1, const float* __restrict__ W2,
                bf16* __restrict__ oqkv, bf16* __restrict__ o0,
                bf16* __restrict__ o1, bf16* __restrict__ o2)
{
    int t = blockIdx.x;
    const float* W; bf16* WT; int K, N; bool perm = false;
    if (t < 768)       {           W = Wqkv; WT = oqkv; K = 512;  N = 1536; perm = true; }
    else if (t < 1024) { t -= 768;  W = W0;  WT = o0;  K = 512;  N = 512;  }
    else if (t < 2048) { t -= 1024; W = W1;  WT = o1;  K = 512;  N = 2048; }
    else               { t -= 2048; W = W2;  WT = o2;  K = 2048; N = 512;  }
    const int nx = N / 32;
    const int n0 = (t % nx) * 32, k0 = (t / nx) * 32;
    __shared__ float tile[32][33];
    const int tx = threadIdx.x & 31, ty = threadIdx.x >> 5;
#pragma unroll
    for (int i = 0; i < 4; ++i)
        tile[ty + i * 8][tx] = W[(long)(k0 + ty + i * 8) * N + n0 + tx];
    __syncthreads();
#pragma unroll
    for (int i = 0; i < 4; ++i) {
        int n = n0 + ty + i * 8;
        if (perm) {
            const int d = n / 12, rr = n % 12;
            n = (rr >> 2) * 512 + (rr & 3) * 128 + d;
        }
        WT[(long)n * K + k0 + tx] = __float2bfloat16(tile[tx][ty + i * 8]);
    }
}

// ---------------------------------------------------------------------------
// Patch gather: img (Bc,3,384,384) -> pat[b*576 + x*24+y][p1*48 + p2*3 + c] bf16
// ---------------------------------------------------------------------------
__global__ __launch_bounds__(64)
void patch_gather(const float* __restrict__ img, bf16* __restrict__ pat)
{
    const int bid = blockIdx.x;
    const int x  = bid % 24;
    const int p1 = (bid / 24) % 16;
    const int b  = bid / (24 * 16);
    __shared__ bf16 lds[24][48];
    const int lane = threadIdx.x;
    const int h = p1 * 24 + x;
    for (int c = 0; c < 3; ++c) {
        const float* row = img + ((long)(b * 3 + c) * 384 + h) * 384;
#pragma unroll
        for (int i = 0; i < 6; ++i) {
            const int wpix = lane + i * 64;
            const float v = row[wpix];
            const int y = wpix % 24, p2 = wpix / 24;
            lds[y][p2 * 3 + c] = __float2bfloat16(v);
        }
    }
    __syncthreads();
    for (int idx = lane; idx < 24 * 48; idx += 64) {
        const int y = idx / 48, j = idx % 48;
        pat[(long)(b * 576 + x * 24 + y) * 768 + p1 * 48 + j] = lds[y][j];
    }
}

// cls token row
__global__ __launch_bounds__(256)
void clsfill(const float* __restrict__ cls, const float* __restrict__ pos,
             float* __restrict__ tokf, bf16* __restrict__ xb)
{
    const int i = blockIdx.x * 256 + threadIdx.x;
    const int b = i >> 9, d = i & 511;
    const float v = cls[d] + pos[d];
    tokf[(long)b * TOKENS * DMODEL + d] = v;
    xb[(long)b * TOKENS * DMODEL + d] = __float2bfloat16(v);
}

// ---------------------------------------------------------------------------
// v (qkv permuted col 1024 + h*128 + d) -> vhT[(pair)*128 + d][t], t>=577 -> 0
// ---------------------------------------------------------------------------
__global__ __launch_bounds__(256)
void repack_v(const u16* __restrict__ qkv, u16* __restrict__ vhT)
{
    __shared__ u16 lds[64][136];
    const int bid = blockIdx.x;               // (pair, tt)
    const int tt = bid % 10, pair = bid / 10;
    const int b = pair >> 2, h = pair & 3;
    const int tid = threadIdx.x;
    const int tl = tid >> 2, seg = tid & 3;
    const long row = (long)b * TOKENS + tt * 64 + tl;
    const u16* src = qkv + row * 1536 + 1024 + h * 128 + seg * 32;
#pragma unroll
    for (int u = 0; u < 4; ++u)
        *(uint4*)&lds[tl][seg * 32 + u * 8] = *(const uint4*)&src[u * 8];
    __syncthreads();
    const int d = tid >> 1, th = (tid & 1) * 32;
    u16* dst = vhT + ((long)pair * 128 + d) * TPAD + tt * 64 + th;
#pragma unroll
    for (int blk = 0; blk < 4; ++blk) {
        uint4 pk; u16* pp = (u16*)&pk;
#pragma unroll
        for (int j = 0; j < 8; ++j) {
            const int t = tt * 64 + th + blk * 8 + j;
            pp[j] = (t < TOKENS) ? lds[th + blk * 8 + j][d] : (u16)0;
        }
        *(uint4*)&dst[blk * 8] = pk;
    }
}

// ---------------------------------------------------------------------------
// y = LN(xin(bf16) + res(f32))*g + b  -> outf (may alias res) and outb (bf16)
// ---------------------------------------------------------------------------
__global__ __launch_bounds__(256)
void resln(const bf16* __restrict__ xin, const float* __restrict__ res,
           const float* __restrict__ g, const float* __restrict__ b,
           float* __restrict__ outf, bf16* __restrict__ outb, int nrows)
{
    const int row = blockIdx.x * 4 + (threadIdx.x >> 6);
    if (row >= nrows) return;
    const int lane = threadIdx.x & 63;
    const bf16* p1 = xin + (long)row * DMODEL;
    const float* p2 = res + (long)row * DMODEL;
    float v[8];
    float s = 0.f;
#pragma unroll
    for (int i = 0; i < 8; ++i) {
        v[i] = __bfloat162float(p1[lane + i * 64]) + p2[lane + i * 64];
        s += v[i];
    }
#pragma unroll
    for (int o = 32; o; o >>= 1) s += __shfl_xor(s, o);
    const float mean = s * (1.f / 512.f);
    float q = 0.f;
#pragma unroll
    for (int i = 0; i < 8; ++i) { const float d = v[i] - mean; q += d * d; }
#pragma unroll
    for (int o = 32; o; o >>= 1) q += __shfl_xor(q, o);
    const float rs = rsqrtf(q * (1.f / 512.f) + 1e-5f);
#pragma unroll
    for (int i = 0; i < 8; ++i) {
        const int c = lane + i * 64;
        const float o = (v[i] - mean) * rs * g[c] + b[c];
        outf[(long)row * DMODEL + c] = o;
        outb[(long)row * DMODEL + c] = __float2bfloat16(o);
    }
}

// Head: out[b][c] = tok[b*577][:] . Whead[:,c] + bhead[c]
__global__ __launch_bounds__(64)
void head_k(const float* __restrict__ tokf, const float* __restrict__ Wh,
            const float* __restrict__ bh, float* __restrict__ out)
{
    const int b = blockIdx.x;
    const int lane = threadIdx.x;
    const float* x = tokf + (long)b * TOKENS * DMODEL;
    float acc[10] = {};
#pragma unroll
    for (int i = 0; i < 8; ++i) {
        const int d = lane + i * 64;
        const float xv = x[d];
        const float* wr = Wh + (long)d * 10;
#pragma unroll
        for (int c = 0; c < 10; ++c) acc[c] += xv * wr[c];
    }
#pragma unroll
    for (int c = 0; c < 10; ++c)
#pragma unroll
        for (int o = 32; o; o >>= 1) acc[c] += __shfl_xor(acc[c], o);
    if (lane == 0) {
#pragma unroll
        for (int c = 0; c < 10; ++c) out[b * 10 + c] = acc[c] + bh[c];
    }
}

// ---------------------------------------------------------------------------
extern "C" void kernel_launch(void* const* d_in, const int* in_sizes, int n_in,
                              void* d_out, int out_size, void* d_ws, size_t ws_size,
                              hipStream_t stream)
{
    (void)in_sizes; (void)n_in; (void)out_size;
    const float* img    = (const float*)d_in[0];
    const float* Wpatch = (const float*)d_in[1];
    const float* bpatch = (const float*)d_in[2];
    const float* clstk  = (const float*)d_in[3];
    const float* pos    = (const float*)d_in[4];
    const float* Wqkv   = (const float*)d_in[5];
    const float* W0     = (const float*)d_in[6];
    const float* g1     = (const float*)d_in[7];
    const float* b1     = (const float*)d_in[8];
    const float* g2     = (const float*)d_in[9];
    const float* b2     = (const float*)d_in[10];
    const float* W1     = (const float*)d_in[11];
    const float* bb1    = (const float*)d_in[12];
    const float* W2     = (const float*)d_in[13];
    const float* bb2    = (const float*)d_in[14];
    const float* Whead  = (const float*)d_in[15];
    const float* bhead  = (const float*)d_in[16];

    // ---- pick the largest batch chunk that fits ws (M padded to 128) ----
    static const int cand[6] = {32, 16, 8, 4, 2, 1};
    int Bc = 0;
    size_t o_tokf=0, o_xb=0, o_R1=0, o_R2=0, o_ob=0, o_wp=0, o_wr=0;
    for (int ci = 0; ci < 6; ++ci) {
        const int bc = cand[ci];
        const long Mrows = (long)bc * TOKENS;
        const long Mpad  = ((Mrows + 127) / 128) * 128;
        size_t off = 0;
        auto take = [&](size_t sz) { size_t o = off; off += (sz + 255) & ~(size_t)255; return o; };
        size_t t_tokf = take((size_t)Mpad * 512 * 4);
        size_t t_xb   = take((size_t)Mpad * 512 * 2);
        size_t t_R1   = take((size_t)Mpad * 2048 * 2);          // pat | qkv | h1b
        size_t r2a = (size_t)bc * 4 * TPAD * 128 * 2;           // vhT
        size_t r2b = (size_t)Mpad * 512 * 2;                    // t1 (bf16)
        size_t t_R2 = take(r2a > r2b ? r2a : r2b);
        size_t t_ob   = take((size_t)Mpad * 512 * 2);
        size_t t_wp   = take((size_t)512 * 768 * 2);
        size_t t_wr   = take((size_t)3145728 * 2);              // rotating layer weights
        if (off <= ws_size) {
            Bc = bc;
            o_tokf=t_tokf; o_xb=t_xb; o_R1=t_R1; o_R2=t_R2; o_ob=t_ob; o_wp=t_wp; o_wr=t_wr;
            break;
        }
    }
    if (Bc == 0) return;

    const long Mrows = (long)Bc * TOKENS;
    const long Mpad  = ((Mrows + 127) / 128) * 128;
    const int  NP    = Bc * 4;
    const int  gy    = (int)(Mpad / 128);
    const long patRows = ((long)Bc * 576 + 127) / 128 * 128;

    char* base = (char*)d_ws;
    float* tokf = (float*)(base + o_tokf);
    bf16*  xb   = (bf16*)(base + o_xb);
    char*  R1   = base + o_R1;
    char*  R2   = base + o_R2;
    bf16*  ob   = (bf16*)(base + o_ob);
    bf16*  wpT  = (bf16*)(base + o_wp);
    bf16*  wqkvT = (bf16*)(base + o_wr);
    bf16*  w0T   = wqkvT + 1536 * 512;
    bf16*  w1T   = w0T   + 512 * 512;
    bf16*  w2T   = w1T   + 2048 * 512;

    u16*  qkvb = (u16*)R1;
    bf16* pat  = (bf16*)R1;
    u16*  h1b  = (u16*)R1;
    u16*  vhT  = (u16*)R2;
    bf16* t1b  = (bf16*)R2;

    wtrans<<<dim3(512 / 32, 768 / 32), 256, 0, stream>>>(Wpatch, wpT, 768, 512);

    const int nchunks = 32 / Bc;
    for (int ch = 0; ch < nchunks; ++ch) {
        const float* img_c = img + (long)ch * Bc * 3 * 384 * 384;

        // embed
        hipMemsetAsync(xb, 0, (size_t)Mpad * 512 * 2, stream);   // pad rows -> exact 0
        clsfill<<<Bc * 2, 256, 0, stream>>>(clstk, pos, tokf, xb);
        patch_gather<<<Bc * 16 * 24, 64, 0, stream>>>(img_c, pat);
        gemm_bt<1, false><<<dim3(4, (int)(patRows / 128)), 256, 0, stream>>>(
            (const u16*)pat, 768, (const u16*)wpT, 768,
            tokf, xb, 512, bpatch, pos, 768, Bc * 576);

        for (int l = 0; l < 6; ++l) {
            // all four weight transposes in one launch (rotating buffer)
            wtrans_all<<<3072, 256, 0, stream>>>(
                Wqkv + (long)l * 512 * 1536, W0 + (long)l * 512 * 512,
                W1 + (long)l * 512 * 2048, W2 + (long)l * 2048 * 512,
                wqkvT, w0T, w1T, w2T);

            // qkv = x @ Wqkv  (permuted cols: kk*512 + h*128 + d)
            gemm_bt<0, false><<<dim3(12, gy), 256, 0, stream>>>(
                (const u16*)xb, 512, (const u16*)wqkvT, 512,
                nullptr, (bf16*)qkvb, 1536, nullptr, nullptr, 512, (int)Mpad);

            repack_v<<<NP * 10, 256, 0, stream>>>(qkvb, vhT);
            attn_flash<<<dim3(5, NP), 256, 0, stream>>>(qkvb, vhT, ob);

            // proj: t1b = o @ W0 (bf16; t1b overwrites vhT — attention done)
            gemm_bt<0, false><<<dim3(4, gy), 256, 0, stream>>>(
                (const u16*)ob, 512, (const u16*)w0T, 512,
                nullptr, t1b, 512, nullptr, nullptr, 512, (int)Mrows);
            // y = LN(t1 + x) -> tokf, xb
            resln<<<(int)((Mrows + 3) / 4), 256, 0, stream>>>(
                t1b, tokf, g1 + l * 512, b1 + l * 512, tokf, xb, (int)Mrows);
            // h1 = gelu(y @ W1 + bb1)   (h1b overwrites qkv — dead)
            gemm_bt<0, true><<<dim3(16, gy), 256, 0, stream>>>(
                (const u16*)xb, 512, (const u16*)w1T, 512,
                nullptr, (bf16*)h1b, 2048, bb1 + l * 2048, nullptr, 512, (int)Mpad);
            // t1b = h1 @ W2 + bb2
            gemm_bt<0, false><<<dim3(4, gy), 256, 0, stream>>>(
                (const u16*)h1b, 2048, (const u16*)w2T, 2048,
                nullptr, t1b, 512, bb2 + l * 512, nullptr, 2048, (int)Mrows);
            // x = LN(t1 + y) -> tokf, xb
            resln<<<(int)((Mrows + 3) / 4), 256, 0, stream>>>(
                t1b, tokf, g2 + l * 512, b2 + l * 512, tokf, xb, (int)Mrows);
        }

        head_k<<<Bc, 64, 0, stream>>>(tokf, Whead, bhead, (float*)d_out + (long)ch * Bc * 10);
    }
}

// Round 10
// 3244.701 us; speedup vs baseline: 1.0370x; 1.0370x over previous
//
#include <hip/hip_runtime.h>
#include <hip/hip_bf16.h>

// ViT forward, MI355X. Round-3 m97-style gemm_bt for K=512 GEMMs (best
// measured); round-8 8-phase counted-vmcnt gemm8 for FFN2 only (K=2048 = its
// proper pipeline regime); fused flash attention; f32 residual/LN.

typedef unsigned short u16;
typedef __hip_bfloat16 bf16;
typedef __bf16 bf16x8 __attribute__((ext_vector_type(8)));
typedef float f32x4 __attribute__((ext_vector_type(4)));

typedef const __attribute__((address_space(1))) void* gas_ptr;
typedef __attribute__((address_space(3))) void* las_ptr;

#define TOKENS 577
#define TPAD   640
#define DMODEL 512
#define SM_SCALE 0.08838834764831845f   /* 128^-0.5 */

static __device__ __forceinline__ u16 f2b(float v) {
    bf16 t = __float2bfloat16(v);
    return *(u16*)&t;
}

// ---------------------------------------------------------------------------
// Round-3 GEMM (measured best at K=512): 128x128 tile, BK=64,
// global_load_lds staging, 2 barriers per K-step.
// C[M,N] = A[M,K] @ Bt[N,K]^T (+bias)(+gelu).
// OUTMODE 0: plain. 1: patch-embed epilogue (row remap b*577+1+t, +pos).
// ---------------------------------------------------------------------------
template<int OUTMODE, bool GELU>
__global__ __launch_bounds__(256)
void gemm_bt(const u16* __restrict__ A, int lda,
             const u16* __restrict__ Bt, int ldb,
             float* __restrict__ Cf, bf16* __restrict__ Cb, int ldc,
             const float* __restrict__ bias, const float* __restrict__ pos,
             int K, int rows_valid)
{
    __shared__ u16 As[128 * 64];
    __shared__ u16 Bs[128 * 64];
    const int tid  = threadIdx.x;
    const int w    = tid >> 6;
    const int lane = tid & 63;
    const u16* Ab = A + (long)blockIdx.y * 128 * lda;
    const u16* Bb = Bt + (long)blockIdx.x * 128 * ldb;
    const int srow = w * 8 + (lane >> 3);
    const int scol = (lane & 7) * 8;
    const int wr = w >> 1, wc = w & 1;
    const int lr = lane & 15, lg = lane >> 4;
    f32x4 acc[4][4] = {};

    for (int kt = 0; kt < K; kt += 64) {
#pragma unroll
        for (int i = 0; i < 4; ++i) {
            const u16* ag = Ab + (long)(i * 32 + srow) * lda + kt + scol;
            const u16* bg = Bb + (long)(i * 32 + srow) * ldb + kt + scol;
            __builtin_amdgcn_global_load_lds((gas_ptr)ag, (las_ptr)&As[(i * 32 + w * 8) * 64], 16, 0, 0);
            __builtin_amdgcn_global_load_lds((gas_ptr)bg, (las_ptr)&Bs[(i * 32 + w * 8) * 64], 16, 0, 0);
        }
        __syncthreads();
#pragma unroll
        for (int kk = 0; kk < 2; ++kk) {
            const int ko = kk * 32 + lg * 8;
            bf16x8 af[4], bv[4];
#pragma unroll
            for (int m = 0; m < 4; ++m)
                af[m] = *(const bf16x8*)&As[(wr * 64 + m * 16 + lr) * 64 + ko];
#pragma unroll
            for (int n = 0; n < 4; ++n)
                bv[n] = *(const bf16x8*)&Bs[(wc * 64 + n * 16 + lr) * 64 + ko];
#pragma unroll
            for (int m = 0; m < 4; ++m)
#pragma unroll
                for (int n = 0; n < 4; ++n)
                    acc[m][n] = __builtin_amdgcn_mfma_f32_16x16x32_bf16(af[m], bv[n], acc[m][n], 0, 0, 0);
        }
        __syncthreads();
    }

    const int cbase = blockIdx.x * 128 + wc * 64;
    const int rbase = blockIdx.y * 128 + wr * 64;
#pragma unroll
    for (int n = 0; n < 4; ++n) {
        const int c = cbase + n * 16 + lr;
        const float bval = bias ? bias[c] : 0.0f;
#pragma unroll
        for (int m = 0; m < 4; ++m) {
#pragma unroll
            for (int j = 0; j < 4; ++j) {
                const int r = rbase + m * 16 + lg * 4 + j;
                if (r >= rows_valid) continue;
                float v = acc[m][n][j] + bval;
                if constexpr (GELU) v = 0.5f * v * (1.0f + erff(v * 0.70710678118654752f));
                long idx;
                if constexpr (OUTMODE == 1) {
                    const int pb = r / 576, pt = r - pb * 576;
                    v += pos[(long)(1 + pt) * DMODEL + c];
                    idx = (long)(pb * TOKENS + 1 + pt) * ldc + c;
                } else {
                    idx = (long)r * ldc + c;
                }
                if (Cf) Cf[idx] = v;
                if (Cb) Cb[idx] = __float2bfloat16(v);
            }
        }
    }
}

// ---------------------------------------------------------------------------
// 8-phase GEMM (round-8, refcheck'd): BM=BN=256, BK=64 in two K-halves.
// Counted vmcnt(4), raw s_barrier, T2 swizzle, T5 setprio. Used for FFN2
// (K=2048 = 32 K-tiles -> pipeline fills).
// ---------------------------------------------------------------------------
template<int OUTMODE, bool GELU>
__global__ __launch_bounds__(512, 1)
void gemm8(const u16* __restrict__ A, int lda,
           const u16* __restrict__ Bt, int ldb,
           float* __restrict__ Cf, bf16* __restrict__ Cb, int ldc,
           const float* __restrict__ bias, const float* __restrict__ pos,
           int K, int rows_valid)
{
    __shared__ u16 Ash[2][2][256 * 32];
    __shared__ u16 Bsh[2][2][256 * 32];
    const int tid = threadIdx.x, wid = tid >> 6, lane = tid & 63;
    const int wm = wid >> 2, wn = wid & 3;
    const int lr = lane & 15, lg = lane >> 4;
    const u16* Ab = A + (long)blockIdx.y * 256 * lda;
    const u16* Bb = Bt + (long)blockIdx.x * 256 * ldb;
    const int srow = tid >> 2;
    const int soct = ((tid & 3) ^ (srow & 3)) * 8;
    const int slot8 = (lg ^ (lr & 3)) * 8;

    f32x4 acc[8][4] = {};

    auto stage = [&](u16* dst, const u16* src, int ld, int kt, int kh) {
#pragma unroll
        for (int i = 0; i < 2; ++i)
            __builtin_amdgcn_global_load_lds(
                (gas_ptr)(src + (long)(i * 128 + srow) * ld + kt * 64 + kh * 32 + soct),
                (las_ptr)(dst + (i * 512 + tid) * 8), 16, 0, 0);
    };

#define VMW(n) { asm volatile("s_waitcnt vmcnt(" #n ")" ::: "memory"); \
                 __builtin_amdgcn_sched_barrier(0); }
#define MFMA16(A0)                                                              \
    __builtin_amdgcn_s_setprio(1);                                             \
    _Pragma("unroll")                                                           \
    for (int m = 0; m < 4; ++m)                                                 \
        _Pragma("unroll")                                                       \
        for (int n = 0; n < 4; ++n)                                             \
            acc[(A0) + m][n] = __builtin_amdgcn_mfma_f32_16x16x32_bf16(         \
                af[m], bfr[n], acc[(A0) + m][n], 0, 0, 0);                      \
    __builtin_amdgcn_s_setprio(0);

    const int nt = K / 64;
    stage(&Ash[0][0][0], Ab, lda, 0, 0);
    stage(&Bsh[0][0][0], Bb, ldb, 0, 0);
    stage(&Ash[0][1][0], Ab, lda, 0, 1);
    stage(&Bsh[0][1][0], Bb, ldb, 0, 1);
    VMW(4);
    __builtin_amdgcn_s_barrier();

    for (int t = 0; t < nt; ++t) {
        const int db = t & 1;
        const bool nx = (t + 1 < nt);
        bf16x8 af[4], bfr[4];

        // ph1: kh0, m-half0
#pragma unroll
        for (int n = 0; n < 4; ++n)
            bfr[n] = *(const bf16x8*)&Bsh[db][0][(wn * 64 + n * 16 + lr) * 32 + slot8];
#pragma unroll
        for (int m = 0; m < 4; ++m)
            af[m] = *(const bf16x8*)&Ash[db][0][(wm * 128 + m * 16 + lr) * 32 + slot8];
        if (nx) stage(&Ash[db ^ 1][0][0], Ab, lda, t + 1, 0);
        __builtin_amdgcn_s_barrier();
        MFMA16(0)
        __builtin_amdgcn_s_barrier();

        // ph2: kh0, m-half1
#pragma unroll
        for (int m = 0; m < 4; ++m)
            af[m] = *(const bf16x8*)&Ash[db][0][(wm * 128 + 64 + m * 16 + lr) * 32 + slot8];
        if (nx) { stage(&Bsh[db ^ 1][0][0], Bb, ldb, t + 1, 0); VMW(4); }
        else    { VMW(0); }
        __builtin_amdgcn_s_barrier();
        MFMA16(4)
        __builtin_amdgcn_s_barrier();

        // ph3: kh1, m-half0
#pragma unroll
        for (int n = 0; n < 4; ++n)
            bfr[n] = *(const bf16x8*)&Bsh[db][1][(wn * 64 + n * 16 + lr) * 32 + slot8];
#pragma unroll
        for (int m = 0; m < 4; ++m)
            af[m] = *(const bf16x8*)&Ash[db][1][(wm * 128 + m * 16 + lr) * 32 + slot8];
        if (nx) stage(&Ash[db ^ 1][1][0], Ab, lda, t + 1, 1);
        __builtin_amdgcn_s_barrier();
        MFMA16(0)
        __builtin_amdgcn_s_barrier();

        // ph4: kh1, m-half1
#pragma unroll
        for (int m = 0; m < 4; ++m)
            af[m] = *(const bf16x8*)&Ash[db][1][(wm * 128 + 64 + m * 16 + lr) * 32 + slot8];
        if (nx) { stage(&Bsh[db ^ 1][1][0], Bb, ldb, t + 1, 1); VMW(4); }
        __builtin_amdgcn_s_barrier();
        MFMA16(4)
        __builtin_amdgcn_s_barrier();
    }
#undef MFMA16
#undef VMW

    const int cbase = blockIdx.x * 256 + wn * 64;
    const int rbase = blockIdx.y * 256 + wm * 128;
#pragma unroll
    for (int n = 0; n < 4; ++n) {
        const int c = cbase + n * 16 + lr;
        const float bval = bias ? bias[c] : 0.0f;
#pragma unroll
        for (int a = 0; a < 8; ++a) {
#pragma unroll
            for (int j = 0; j < 4; ++j) {
                const int r = rbase + a * 16 + lg * 4 + j;
                if (r >= rows_valid) continue;
                float v = acc[a][n][j] + bval;
                if constexpr (GELU) v = 0.5f * v * (1.0f + erff(v * 0.70710678118654752f));
                long idx;
                if constexpr (OUTMODE == 1) {
                    const int pb = r / 576, pt = r - pb * 576;
                    v += pos[(long)(1 + pt) * DMODEL + c];
                    idx = (long)(pb * TOKENS + 1 + pt) * ldc + c;
                } else {
                    idx = (long)r * ldc + c;
                }
                if (Cf) Cf[idx] = v;
                if (Cb) Cb[idx] = __float2bfloat16(v);
            }
        }
    }
}

// ---------------------------------------------------------------------------
// Fused flash attention (round-3 verified). Grid: (5 q-tiles, NP pairs).
// qkv layout (permuted): [row][ kk*512 + h*128 + d ], row = b*577 + t (+pad).
// ---------------------------------------------------------------------------
__global__ __launch_bounds__(256, 2)
void attn_flash(const u16* __restrict__ qkv, const u16* __restrict__ vhT,
                bf16* __restrict__ ob)
{
    __shared__ u16 ldsA[128 * 128];
    __shared__ u16 ldsB[128 * 128];
    const int tid = threadIdx.x;
    const int w = tid >> 6, lane = tid & 63;
    const int lr = lane & 15, lg = lane >> 4;
    const int pair = blockIdx.y;
    const int b = pair >> 2, h = pair & 3;
    const int q0 = blockIdx.x * 128;
    const long rowbase = (long)b * TOKENS;

    bf16x8 qf[2][4];
#pragma unroll
    for (int m = 0; m < 2; ++m)
#pragma unroll
        for (int kf = 0; kf < 4; ++kf) {
            const long r = rowbase + q0 + w * 32 + m * 16 + lr;
            qf[m][kf] = *(const bf16x8*)&qkv[r * 1536 + h * 128 + kf * 32 + lg * 8];
        }

    float mrun[2][4], lrun[2][4];
#pragma unroll
    for (int m = 0; m < 2; ++m)
#pragma unroll
        for (int j = 0; j < 4; ++j) { mrun[m][j] = -1e30f; lrun[m][j] = 0.f; }
    f32x4 oacc[2][8] = {};

    for (int kv0 = 0; kv0 < TPAD; kv0 += 128) {
        {
            const u16* kg = qkv + (rowbase + kv0) * 1536 + 512 + h * 128;
            const u16* vg = vhT + ((long)pair * 128) * TPAD + kv0;
#pragma unroll
            for (int p = 0; p < 8; ++p) {
                const int i = p * 16 + w * 4 + lg;
                __builtin_amdgcn_global_load_lds((gas_ptr)(kg + (long)i * 1536 + lr * 8),
                                                 (las_ptr)&ldsA[(p * 16 + w * 4) * 128], 16, 0, 0);
                __builtin_amdgcn_global_load_lds((gas_ptr)(vg + (long)i * TPAD + lr * 8),
                                                 (las_ptr)&ldsB[(p * 16 + w * 4) * 128], 16, 0, 0);
            }
        }
        __syncthreads();

        f32x4 s[2][8] = {};
#pragma unroll
        for (int kf = 0; kf < 4; ++kf) {
            bf16x8 bv[8];
#pragma unroll
            for (int n = 0; n < 8; ++n)
                bv[n] = *(const bf16x8*)&ldsA[(n * 16 + lr) * 128 + kf * 32 + lg * 8];
            __builtin_amdgcn_s_setprio(1);
#pragma unroll
            for (int m = 0; m < 2; ++m)
#pragma unroll
                for (int n = 0; n < 8; ++n)
                    s[m][n] = __builtin_amdgcn_mfma_f32_16x16x32_bf16(qf[m][kf], bv[n], s[m][n], 0, 0, 0);
            __builtin_amdgcn_s_setprio(0);
        }

        float sc[2][4];
#pragma unroll
        for (int m = 0; m < 2; ++m)
#pragma unroll
            for (int jj = 0; jj < 4; ++jj) {
                float mx = mrun[m][jj];
#pragma unroll
                for (int n = 0; n < 8; ++n) {
                    const int col = kv0 + n * 16 + lr;
                    float v = s[m][n][jj] * SM_SCALE;
                    v = (col < TOKENS) ? v : -1e30f;
                    s[m][n][jj] = v;
                    mx = fmaxf(mx, v);
                }
#pragma unroll
                for (int o = 1; o < 16; o <<= 1) mx = fmaxf(mx, __shfl_xor(mx, o));
                const float f = __expf(mrun[m][jj] - mx);
                sc[m][jj] = f;
                float sum = 0.f;
#pragma unroll
                for (int n = 0; n < 8; ++n) {
                    const float p = __expf(s[m][n][jj] - mx);
                    s[m][n][jj] = p;
                    sum += p;
                }
#pragma unroll
                for (int o = 1; o < 16; o <<= 1) sum += __shfl_xor(sum, o);
                lrun[m][jj] = lrun[m][jj] * f + sum;
                mrun[m][jj] = mx;
            }
#pragma unroll
        for (int m = 0; m < 2; ++m)
#pragma unroll
            for (int n = 0; n < 8; ++n)
#pragma unroll
                for (int jj = 0; jj < 4; ++jj) oacc[m][n][jj] *= sc[m][jj];

        __syncthreads();
#pragma unroll
        for (int m = 0; m < 2; ++m)
#pragma unroll
            for (int n = 0; n < 8; ++n)
#pragma unroll
                for (int jj = 0; jj < 4; ++jj)
                    ldsA[(w * 32 + m * 16 + lg * 4 + jj) * 128 + n * 16 + lr] = f2b(s[m][n][jj]);
        __syncthreads();

#pragma unroll
        for (int kf = 0; kf < 4; ++kf) {
            bf16x8 pa[2];
#pragma unroll
            for (int m = 0; m < 2; ++m)
                pa[m] = *(const bf16x8*)&ldsA[(w * 32 + m * 16 + lr) * 128 + kf * 32 + lg * 8];
            __builtin_amdgcn_s_setprio(1);
#pragma unroll
            for (int n = 0; n < 8; ++n) {
                const bf16x8 vb = *(const bf16x8*)&ldsB[(n * 16 + lr) * 128 + kf * 32 + lg * 8];
#pragma unroll
                for (int m = 0; m < 2; ++m)
                    oacc[m][n] = __builtin_amdgcn_mfma_f32_16x16x32_bf16(pa[m], vb, oacc[m][n], 0, 0, 0);
            }
            __builtin_amdgcn_s_setprio(0);
        }
        __syncthreads();
    }

#pragma unroll
    for (int m = 0; m < 2; ++m)
#pragma unroll
        for (int jj = 0; jj < 4; ++jj) {
            const float inv = 1.f / lrun[m][jj];
            const int q = q0 + w * 32 + m * 16 + lg * 4 + jj;
            if (q >= TOKENS) continue;
#pragma unroll
            for (int n = 0; n < 8; ++n)
                ob[(rowbase + q) * DMODEL + h * 128 + n * 16 + lr] =
                    __float2bfloat16(oacc[m][n][jj] * inv);
        }
}

// ---------------------------------------------------------------------------
// Weight transpose + f32->bf16:  WT[n][k] = bf16(W[k][n]).
// QKVPERM: output row n' = kk*512 + h*128 + d  for original col n = d*12+kk*4+h
// ---------------------------------------------------------------------------
template<bool QKVPERM>
__global__ __launch_bounds__(256)
void wtrans(const float* __restrict__ W, bf16* __restrict__ WT, int K, int N)
{
    __shared__ float tile[32][33];
    const int n0 = blockIdx.x * 32, k0 = blockIdx.y * 32;
    const int tx = threadIdx.x & 31, ty = threadIdx.x >> 5;
#pragma unroll
    for (int i = 0; i < 4; ++i)
        tile[ty + i * 8][tx] = W[(long)(k0 + ty + i * 8) * N + n0 + tx];
    __syncthreads();
#pragma unroll
    for (int i = 0; i < 4; ++i) {
        int n = n0 + ty + i * 8;
        if constexpr (QKVPERM) {
            const int d = n / 12, r = n % 12;
            n = (r >> 2) * 512 + (r & 3) * 128 + d;
        }
        WT[(long)n * K + k0 + tx] = __float2bfloat16(tile[tx][ty + i * 8]);
    }
}

// ---------------------------------------------------------------------------
// Patch gather: img (Bc,3,384,384) -> pat[b*576 + x*24+y][p1*48 + p2*3 + c] bf16
// ---------------------------------------------------------------------------
__global__ __launch_bounds__(64)
void patch_gather(const float* __restrict__ img, bf16* __restrict__ pat)
{
    const int bid = blockIdx.x;
    const int x  = bid % 24;
    const int p1 = (bid / 24) % 16;
    const int b  = bid / (24 * 16);
    __shared__ bf16 lds[24][48];
    const int lane = threadIdx.x;
    const int h = p1 * 24 + x;
    for (int c = 0; c < 3; ++c) {
        const float* row = img + ((long)(b * 3 + c) * 384 + h) * 384;
#pragma unroll
        for (int i = 0; i < 6; ++i) {
            const int wpix = lane + i * 64;
            const float v = row[wpix];
            const int y = wpix % 24, p2 = wpix / 24;
            lds[y][p2 * 3 + c] = __float2bfloat16(v);
        }
    }
    __syncthreads();
    for (int idx = lane; idx < 24 * 48; idx += 64) {
        const int y = idx / 48, j = idx % 48;
        pat[(long)(b * 576 + x * 24 + y) * 768 + p1 * 48 + j] = lds[y][j];
    }
}

// cls token row
__global__ __launch_bounds__(256)
void clsfill(const float* __restrict__ cls, const float* __restrict__ pos,
             float* __restrict__ tokf, bf16* __restrict__ xb)
{
    const int i = blockIdx.x * 256 + threadIdx.x;
    const int b = i >> 9, d = i & 511;
    const float v = cls[d] + pos[d];
    tokf[(long)b * TOKENS * DMODEL + d] = v;
    xb[(long)b * TOKENS * DMODEL + d] = __float2bfloat16(v);
}

// ---------------------------------------------------------------------------
// v (qkv permuted col 1024 + h*128 + d) -> vhT[(pair)*128 + d][t], t>=577 -> 0
// ---------------------------------------------------------------------------
__global__ __launch_bounds__(256)
void repack_v(const u16* __restrict__ qkv, u16* __restrict__ vhT)
{
    __shared__ u16 lds[64][136];
    const int bid = blockIdx.x;               // (pair, tt)
    const int tt = bid % 10, pair = bid / 10;
    const int b = pair >> 2, h = pair & 3;
    const int tid = threadIdx.x;
    const int tl = tid >> 2, seg = tid & 3;
    const long row = (long)b * TOKENS + tt * 64 + tl;
    const u16* src = qkv + row * 1536 + 1024 + h * 128 + seg * 32;
#pragma unroll
    for (int u = 0; u < 4; ++u)
        *(uint4*)&lds[tl][seg * 32 + u * 8] = *(const uint4*)&src[u * 8];
    __syncthreads();
    const int d = tid >> 1, th = (tid & 1) * 32;
    u16* dst = vhT + ((long)pair * 128 + d) * TPAD + tt * 64 + th;
#pragma unroll
    for (int blk = 0; blk < 4; ++blk) {
        uint4 pk; u16* pp = (u16*)&pk;
#pragma unroll
        for (int j = 0; j < 8; ++j) {
            const int t = tt * 64 + th + blk * 8 + j;
            pp[j] = (t < TOKENS) ? lds[th + blk * 8 + j][d] : (u16)0;
        }
        *(uint4*)&dst[blk * 8] = pk;
    }
}

// ---------------------------------------------------------------------------
// y = LN(xin + res)*g + b  -> outf (may alias res) and outb (bf16)
// ---------------------------------------------------------------------------
__global__ __launch_bounds__(256)
void resln(const float* __restrict__ xin, const float* __restrict__ res,
           const float* __restrict__ g, const float* __restrict__ b,
           float* __restrict__ outf, bf16* __restrict__ outb, int nrows)
{
    const int row = blockIdx.x * 4 + (threadIdx.x >> 6);
    if (row >= nrows) return;
    const int lane = threadIdx.x & 63;
    const float* p1 = xin + (long)row * DMODEL;
    const float* p2 = res + (long)row * DMODEL;
    float v[8];
    float s = 0.f;
#pragma unroll
    for (int i = 0; i < 8; ++i) { v[i] = p1[lane + i * 64] + p2[lane + i * 64]; s += v[i]; }
#pragma unroll
    for (int o = 32; o; o >>= 1) s += __shfl_xor(s, o);
    const float mean = s * (1.f / 512.f);
    float q = 0.f;
#pragma unroll
    for (int i = 0; i < 8; ++i) { const float d = v[i] - mean; q += d * d; }
#pragma unroll
    for (int o = 32; o; o >>= 1) q += __shfl_xor(q, o);
    const float rs = rsqrtf(q * (1.f / 512.f) + 1e-5f);
#pragma unroll
    for (int i = 0; i < 8; ++i) {
        const int c = lane + i * 64;
        const float o = (v[i] - mean) * rs * g[c] + b[c];
        outf[(long)row * DMODEL + c] = o;
        outb[(long)row * DMODEL + c] = __float2bfloat16(o);
    }
}

// Head: out[b][c] = tok[b*577][:] . Whead[:,c] + bhead[c]
__global__ __launch_bounds__(64)
void head_k(const float* __restrict__ tokf, const float* __restrict__ Wh,
            const float* __restrict__ bh, float* __restrict__ out)
{
    const int b = blockIdx.x;
    const int lane = threadIdx.x;
    const float* x = tokf + (long)b * TOKENS * DMODEL;
    float acc[10] = {};
#pragma unroll
    for (int i = 0; i < 8; ++i) {
        const int d = lane + i * 64;
        const float xv = x[d];
        const float* wr = Wh + (long)d * 10;
#pragma unroll
        for (int c = 0; c < 10; ++c) acc[c] += xv * wr[c];
    }
#pragma unroll
    for (int c = 0; c < 10; ++c)
#pragma unroll
        for (int o = 32; o; o >>= 1) acc[c] += __shfl_xor(acc[c], o);
    if (lane == 0) {
#pragma unroll
        for (int c = 0; c < 10; ++c) out[b * 10 + c] = acc[c] + bh[c];
    }
}

// ---------------------------------------------------------------------------
extern "C" void kernel_launch(void* const* d_in, const int* in_sizes, int n_in,
                              void* d_out, int out_size, void* d_ws, size_t ws_size,
                              hipStream_t stream)
{
    (void)in_sizes; (void)n_in; (void)out_size;
    const float* img    = (const float*)d_in[0];
    const float* Wpatch = (const float*)d_in[1];
    const float* bpatch = (const float*)d_in[2];
    const float* clstk  = (const float*)d_in[3];
    const float* pos    = (const float*)d_in[4];
    const float* Wqkv   = (const float*)d_in[5];
    const float* W0     = (const float*)d_in[6];
    const float* g1     = (const float*)d_in[7];
    const float* b1     = (const float*)d_in[8];
    const float* g2     = (const float*)d_in[9];
    const float* b2     = (const float*)d_in[10];
    const float* W1     = (const float*)d_in[11];
    const float* bb1    = (const float*)d_in[12];
    const float* W2     = (const float*)d_in[13];
    const float* bb2    = (const float*)d_in[14];
    const float* Whead  = (const float*)d_in[15];
    const float* bhead  = (const float*)d_in[16];

    // ---- pick the largest batch chunk that fits ws (M padded to 256) ----
    static const int cand[6] = {32, 16, 8, 4, 2, 1};
    int Bc = 0;
    size_t o_tokf=0, o_xb=0, o_R1=0, o_R2=0, o_ob=0, o_wp=0, o_wr=0;
    for (int ci = 0; ci < 6; ++ci) {
        const int bc = cand[ci];
        const long Mrows = (long)bc * TOKENS;
        const long Mpad  = ((Mrows + 255) / 256) * 256;
        size_t off = 0;
        auto take = [&](size_t sz) { size_t o = off; off += (sz + 255) & ~(size_t)255; return o; };
        size_t t_tokf = take((size_t)Mpad * 512 * 4);
        size_t t_xb   = take((size_t)Mpad * 512 * 2);
        size_t t_R1   = take((size_t)Mpad * 2048 * 2);          // pat | qkv | h1b
        size_t r2a = (size_t)bc * 4 * TPAD * 128 * 2;           // vhT
        size_t r2b = (size_t)Mpad * 512 * 4;                    // t1 (f32)
        size_t t_R2 = take(r2a > r2b ? r2a : r2b);
        size_t t_ob   = take((size_t)Mpad * 512 * 2);
        size_t t_wp   = take((size_t)512 * 768 * 2);
        size_t t_wr   = take((size_t)3145728 * 2);              // rotating layer weights
        if (off <= ws_size) {
            Bc = bc;
            o_tokf=t_tokf; o_xb=t_xb; o_R1=t_R1; o_R2=t_R2; o_ob=t_ob; o_wp=t_wp; o_wr=t_wr;
            break;
        }
    }
    if (Bc == 0) return;

    const long Mrows = (long)Bc * TOKENS;
    const long Mpad  = ((Mrows + 255) / 256) * 256;
    const int  NP    = Bc * 4;
    const int  gy128 = (int)(Mpad / 128);
    const int  gy256 = (int)(Mpad / 256);
    const long patRows = ((long)Bc * 576 + 127) / 128 * 128;

    char* base = (char*)d_ws;
    float* tokf = (float*)(base + o_tokf);
    bf16*  xb   = (bf16*)(base + o_xb);
    char*  R1   = base + o_R1;
    char*  R2   = base + o_R2;
    bf16*  ob   = (bf16*)(base + o_ob);
    bf16*  wpT  = (bf16*)(base + o_wp);
    bf16*  wqkvT = (bf16*)(base + o_wr);
    bf16*  w0T   = wqkvT + 1536 * 512;
    bf16*  w1T   = w0T   + 512 * 512;
    bf16*  w2T   = w1T   + 2048 * 512;

    u16*  qkvb = (u16*)R1;
    bf16* pat  = (bf16*)R1;
    u16*  h1b  = (u16*)R1;
    u16*  vhT  = (u16*)R2;
    float* t1  = (float*)R2;

    wtrans<false><<<dim3(512 / 32, 768 / 32), 256, 0, stream>>>(Wpatch, wpT, 768, 512);

    const int nchunks = 32 / Bc;
    for (int ch = 0; ch < nchunks; ++ch) {
        const float* img_c = img + (long)ch * Bc * 3 * 384 * 384;

        // embed
        hipMemsetAsync(xb, 0, (size_t)Mpad * 512 * 2, stream);   // pad rows -> exact 0
        clsfill<<<Bc * 2, 256, 0, stream>>>(clstk, pos, tokf, xb);
        patch_gather<<<Bc * 16 * 24, 64, 0, stream>>>(img_c, pat);
        gemm_bt<1, false><<<dim3(4, (int)(patRows / 128)), 256, 0, stream>>>(
            (const u16*)pat, 768, (const u16*)wpT, 768,
            tokf, xb, 512, bpatch, pos, 768, Bc * 576);

        for (int l = 0; l < 6; ++l) {
            // rotate this layer's weights to bf16 N x K (Wqkv column-permuted)
            wtrans<true ><<<dim3(1536 / 32, 512 / 32), 256, 0, stream>>>(
                Wqkv + (long)l * 512 * 1536, wqkvT, 512, 1536);
            wtrans<false><<<dim3(512 / 32, 512 / 32), 256, 0, stream>>>(
                W0 + (long)l * 512 * 512, w0T, 512, 512);
            wtrans<false><<<dim3(2048 / 32, 512 / 32), 256, 0, stream>>>(
                W1 + (long)l * 512 * 2048, w1T, 512, 2048);
            wtrans<false><<<dim3(512 / 32, 2048 / 32), 256, 0, stream>>>(
                W2 + (long)l * 2048 * 512, w2T, 2048, 512);

            // qkv = x @ Wqkv  (permuted cols: kk*512 + h*128 + d)
            gemm_bt<0, false><<<dim3(12, gy128), 256, 0, stream>>>(
                (const u16*)xb, 512, (const u16*)wqkvT, 512,
                nullptr, (bf16*)qkvb, 1536, nullptr, nullptr, 512, (int)Mpad);

            repack_v<<<NP * 10, 256, 0, stream>>>(qkvb, vhT);
            attn_flash<<<dim3(5, NP), 256, 0, stream>>>(qkvb, vhT, ob);

            // proj: t1 = o @ W0   (t1 overwrites vhT — attention done)
            gemm_bt<0, false><<<dim3(4, gy128), 256, 0, stream>>>(
                (const u16*)ob, 512, (const u16*)w0T, 512,
                t1, nullptr, 512, nullptr, nullptr, 512, (int)Mrows);
            // y = LN(t1 + x) -> tokf, xb
            resln<<<(int)((Mrows + 3) / 4), 256, 0, stream>>>(
                t1, tokf, g1 + l * 512, b1 + l * 512, tokf, xb, (int)Mrows);
            // h1 = gelu(y @ W1 + bb1)   (h1b overwrites qkv — dead)
            gemm_bt<0, true><<<dim3(16, gy128), 256, 0, stream>>>(
                (const u16*)xb, 512, (const u16*)w1T, 512,
                nullptr, (bf16*)h1b, 2048, bb1 + l * 2048, nullptr, 512, (int)Mpad);
            // t1 = h1 @ W2 + bb2  (K=2048 -> 8-phase pipeline)
            gemm8<0, false><<<dim3(2, gy256), 512, 0, stream>>>(
                (const u16*)h1b, 2048, (const u16*)w2T, 2048,
                t1, nullptr, 512, bb2 + l * 512, nullptr, 2048, (int)Mrows);
            // x = LN(t1 + y) -> tokf, xb
            resln<<<(int)((Mrows + 3) / 4), 256, 0, stream>>>(
                t1, tokf, g2 + l * 512, b2 + l * 512, tokf, xb, (int)Mrows);
        }

        head_k<<<Bc, 64, 0, stream>>>(tokf, Whead, bhead, (float*)d_out + (long)ch * Bc * 10);
    }
}

// Round 11
// 3156.087 us; speedup vs baseline: 1.0661x; 1.0281x over previous
//
#include <hip/hip_runtime.h>
#include <hip/hip_bf16.h>

// ViT forward, MI355X. Round-3 gemm_bt (qkv/patch), BK=32 swizzled gemm_bt32
// (FFN1), 8-phase gemm8 (FFN2, K=2048), fused proj+residual+LN1 (proj_ln),
// all-layer weight transpose done once, fused flash attention.

typedef unsigned short u16;
typedef __hip_bfloat16 bf16;
typedef __bf16 bf16x8 __attribute__((ext_vector_type(8)));
typedef float f32x4 __attribute__((ext_vector_type(4)));

typedef const __attribute__((address_space(1))) void* gas_ptr;
typedef __attribute__((address_space(3))) void* las_ptr;

#define TOKENS 577
#define TPAD   640
#define DMODEL 512
#define SM_SCALE 0.08838834764831845f   /* 128^-0.5 */
#define LAYER_W 3145728l                /* bf16 elems per layer's weights */

static __device__ __forceinline__ u16 f2b(float v) {
    bf16 t = __float2bfloat16(v);
    return *(u16*)&t;
}

// ---------------------------------------------------------------------------
// Round-3 GEMM (measured best at K=512): 128x128 tile, BK=64.
// OUTMODE 0: plain. 1: patch-embed epilogue (row remap b*577+1+t, +pos).
// ---------------------------------------------------------------------------
template<int OUTMODE, bool GELU>
__global__ __launch_bounds__(256)
void gemm_bt(const u16* __restrict__ A, int lda,
             const u16* __restrict__ Bt, int ldb,
             float* __restrict__ Cf, bf16* __restrict__ Cb, int ldc,
             const float* __restrict__ bias, const float* __restrict__ pos,
             int K, int rows_valid)
{
    __shared__ u16 As[128 * 64];
    __shared__ u16 Bs[128 * 64];
    const int tid  = threadIdx.x;
    const int w    = tid >> 6;
    const int lane = tid & 63;
    const u16* Ab = A + (long)blockIdx.y * 128 * lda;
    const u16* Bb = Bt + (long)blockIdx.x * 128 * ldb;
    const int srow = w * 8 + (lane >> 3);
    const int scol = (lane & 7) * 8;
    const int wr = w >> 1, wc = w & 1;
    const int lr = lane & 15, lg = lane >> 4;
    f32x4 acc[4][4] = {};

    for (int kt = 0; kt < K; kt += 64) {
#pragma unroll
        for (int i = 0; i < 4; ++i) {
            const u16* ag = Ab + (long)(i * 32 + srow) * lda + kt + scol;
            const u16* bg = Bb + (long)(i * 32 + srow) * ldb + kt + scol;
            __builtin_amdgcn_global_load_lds((gas_ptr)ag, (las_ptr)&As[(i * 32 + w * 8) * 64], 16, 0, 0);
            __builtin_amdgcn_global_load_lds((gas_ptr)bg, (las_ptr)&Bs[(i * 32 + w * 8) * 64], 16, 0, 0);
        }
        __syncthreads();
#pragma unroll
        for (int kk = 0; kk < 2; ++kk) {
            const int ko = kk * 32 + lg * 8;
            bf16x8 af[4], bv[4];
#pragma unroll
            for (int m = 0; m < 4; ++m)
                af[m] = *(const bf16x8*)&As[(wr * 64 + m * 16 + lr) * 64 + ko];
#pragma unroll
            for (int n = 0; n < 4; ++n)
                bv[n] = *(const bf16x8*)&Bs[(wc * 64 + n * 16 + lr) * 64 + ko];
#pragma unroll
            for (int m = 0; m < 4; ++m)
#pragma unroll
                for (int n = 0; n < 4; ++n)
                    acc[m][n] = __builtin_amdgcn_mfma_f32_16x16x32_bf16(af[m], bv[n], acc[m][n], 0, 0, 0);
        }
        __syncthreads();
    }

    const int cbase = blockIdx.x * 128 + wc * 64;
    const int rbase = blockIdx.y * 128 + wr * 64;
#pragma unroll
    for (int n = 0; n < 4; ++n) {
        const int c = cbase + n * 16 + lr;
        const float bval = bias ? bias[c] : 0.0f;
#pragma unroll
        for (int m = 0; m < 4; ++m) {
#pragma unroll
            for (int j = 0; j < 4; ++j) {
                const int r = rbase + m * 16 + lg * 4 + j;
                if (r >= rows_valid) continue;
                float v = acc[m][n][j] + bval;
                if constexpr (GELU) v = 0.5f * v * (1.0f + erff(v * 0.70710678118654752f));
                long idx;
                if constexpr (OUTMODE == 1) {
                    const int pb = r / 576, pt = r - pb * 576;
                    v += pos[(long)(1 + pt) * DMODEL + c];
                    idx = (long)(pb * TOKENS + 1 + pt) * ldc + c;
                } else {
                    idx = (long)r * ldc + c;
                }
                if (Cf) Cf[idx] = v;
                if (Cb) Cb[idx] = __float2bfloat16(v);
            }
        }
    }
}

// ---------------------------------------------------------------------------
// BK=32 variant for FFN1: 16 KB LDS (more resident blocks -> drains of
// independent blocks interleave), XOR-swizzled granules (conflict-free
// ds_read_b128: granule' = lg ^ ((row>>1)&3), 2-way = free).
// ---------------------------------------------------------------------------
template<bool GELU>
__global__ __launch_bounds__(256)
void gemm_bt32(const u16* __restrict__ A, int lda,
               const u16* __restrict__ Bt, int ldb,
               bf16* __restrict__ Cb, int ldc,
               const float* __restrict__ bias, int K, int rows_valid)
{
    __shared__ u16 As[128 * 32];
    __shared__ u16 Bs[128 * 32];
    const int tid  = threadIdx.x;
    const int w    = tid >> 6;
    const int lane = tid & 63;
    const u16* Ab = A + (long)blockIdx.y * 128 * lda;
    const u16* Bb = Bt + (long)blockIdx.x * 128 * ldb;
    const int wr = w >> 1, wc = w & 1;
    const int lr = lane & 15, lg = lane >> 4;
    f32x4 acc[4][4] = {};

    for (int kt = 0; kt < K; kt += 32) {
#pragma unroll
        for (int rd = 0; rd < 2; ++rd) {
            const int idx = rd * 256 + tid;           // 0..511
            const int row = idx >> 2, g = idx & 3;
            const int sg = g ^ ((row >> 1) & 3);      // pre-swizzled src granule
            __builtin_amdgcn_global_load_lds(
                (gas_ptr)(Ab + (long)row * lda + kt + sg * 8), (las_ptr)&As[idx * 8], 16, 0, 0);
            __builtin_amdgcn_global_load_lds(
                (gas_ptr)(Bb + (long)row * ldb + kt + sg * 8), (las_ptr)&Bs[idx * 8], 16, 0, 0);
        }
        __syncthreads();
        bf16x8 af[4], bv[4];
#pragma unroll
        for (int m = 0; m < 4; ++m) {
            const int r = wr * 64 + m * 16 + lr;
            af[m] = *(const bf16x8*)&As[r * 32 + (lg ^ ((r >> 1) & 3)) * 8];
        }
#pragma unroll
        for (int n = 0; n < 4; ++n) {
            const int r = wc * 64 + n * 16 + lr;
            bv[n] = *(const bf16x8*)&Bs[r * 32 + (lg ^ ((r >> 1) & 3)) * 8];
        }
#pragma unroll
        for (int m = 0; m < 4; ++m)
#pragma unroll
            for (int n = 0; n < 4; ++n)
                acc[m][n] = __builtin_amdgcn_mfma_f32_16x16x32_bf16(af[m], bv[n], acc[m][n], 0, 0, 0);
        __syncthreads();
    }

    const int cbase = blockIdx.x * 128 + wc * 64;
    const int rbase = blockIdx.y * 128 + wr * 64;
#pragma unroll
    for (int n = 0; n < 4; ++n) {
        const int c = cbase + n * 16 + lr;
        const float bval = bias ? bias[c] : 0.0f;
#pragma unroll
        for (int m = 0; m < 4; ++m) {
#pragma unroll
            for (int j = 0; j < 4; ++j) {
                const int r = rbase + m * 16 + lg * 4 + j;
                if (r >= rows_valid) continue;
                float v = acc[m][n][j] + bval;
                if constexpr (GELU) v = 0.5f * v * (1.0f + erff(v * 0.70710678118654752f));
                Cb[(long)r * ldc + c] = __float2bfloat16(v);
            }
        }
    }
}

// ---------------------------------------------------------------------------
// Fused proj + residual + LayerNorm: y = LN(ob @ W0 + res) * g + b.
// Block = 64 rows x 512 cols (full row -> LN in epilogue). 8 waves (2M x 4N),
// BK=32, swizzled LDS. Writes tokf (f32) and xb (bf16).
// ---------------------------------------------------------------------------
__global__ __launch_bounds__(512)
void proj_ln(const u16* __restrict__ A, const u16* __restrict__ Bt,
             const float* __restrict__ res,
             const float* __restrict__ g, const float* __restrict__ b,
             float* __restrict__ outf, bf16* __restrict__ outb, int Mrows)
{
    __shared__ u16 As[64 * 32];        // 4 KB
    __shared__ u16 Bs[512 * 32];       // 32 KB
    __shared__ float redS[4][64];
    __shared__ float redQ[4][64];
    const int tid = threadIdx.x, wid = tid >> 6, lane = tid & 63;
    const int wm = wid >> 2, wn = wid & 3;
    const int lr = lane & 15, lg = lane >> 4;
    const long row0 = (long)blockIdx.x * 64;
    const u16* Ab = A + row0 * DMODEL;
    f32x4 acc[2][8] = {};

    for (int kt = 0; kt < 512; kt += 32) {
#pragma unroll
        for (int rd = 0; rd < 4; ++rd) {
            const int idx = rd * 512 + tid;           // B: 0..2047
            const int row = idx >> 2, gg = idx & 3;
            const int sg = gg ^ ((row >> 1) & 3);
            __builtin_amdgcn_global_load_lds(
                (gas_ptr)(Bt + (long)row * DMODEL + kt + sg * 8), (las_ptr)&Bs[idx * 8], 16, 0, 0);
        }
        if (tid < 256) {
            const int row = tid >> 2, gg = tid & 3;
            const int sg = gg ^ ((row >> 1) & 3);
            __builtin_amdgcn_global_load_lds(
                (gas_ptr)(Ab + (long)row * DMODEL + kt + sg * 8), (las_ptr)&As[tid * 8], 16, 0, 0);
        }
        __syncthreads();
        bf16x8 af[2], bv[8];
#pragma unroll
        for (int m = 0; m < 2; ++m) {
            const int r = wm * 32 + m * 16 + lr;
            af[m] = *(const bf16x8*)&As[r * 32 + (lg ^ ((r >> 1) & 3)) * 8];
        }
#pragma unroll
        for (int n = 0; n < 8; ++n) {
            const int r = wn * 128 + n * 16 + lr;
            bv[n] = *(const bf16x8*)&Bs[r * 32 + (lg ^ ((r >> 1) & 3)) * 8];
        }
#pragma unroll
        for (int m = 0; m < 2; ++m)
#pragma unroll
            for (int n = 0; n < 8; ++n)
                acc[m][n] = __builtin_amdgcn_mfma_f32_16x16x32_bf16(af[m], bv[n], acc[m][n], 0, 0, 0);
        __syncthreads();
    }

    // residual add + per-row partial sums (this wave's 128 cols)
    float ps[2][4], pq[2][4];
#pragma unroll
    for (int m = 0; m < 2; ++m)
#pragma unroll
        for (int j = 0; j < 4; ++j) {
            const long r = row0 + wm * 32 + m * 16 + lg * 4 + j;
            const bool valid = r < Mrows;
            float s = 0.f, q = 0.f;
#pragma unroll
            for (int n = 0; n < 8; ++n) {
                float t = acc[m][n][j];
                if (valid) t += res[r * DMODEL + wn * 128 + n * 16 + lr];
                acc[m][n][j] = t;
                s += t; q += t * t;
            }
            ps[m][j] = s; pq[m][j] = q;
        }
#pragma unroll
    for (int o = 1; o < 16; o <<= 1)
#pragma unroll
        for (int m = 0; m < 2; ++m)
#pragma unroll
            for (int j = 0; j < 4; ++j) {
                ps[m][j] += __shfl_xor(ps[m][j], o);
                pq[m][j] += __shfl_xor(pq[m][j], o);
            }
    if (lr == 0) {
#pragma unroll
        for (int m = 0; m < 2; ++m)
#pragma unroll
            for (int j = 0; j < 4; ++j) {
                const int ri = wm * 32 + m * 16 + lg * 4 + j;
                redS[wn][ri] = ps[m][j];
                redQ[wn][ri] = pq[m][j];
            }
    }
    __syncthreads();
    if (tid < 64) {
        const float s = redS[0][tid] + redS[1][tid] + redS[2][tid] + redS[3][tid];
        const float q = redQ[0][tid] + redQ[1][tid] + redQ[2][tid] + redQ[3][tid];
        const float mean = s * (1.f / 512.f);
        const float var = q * (1.f / 512.f) - mean * mean;
        redS[0][tid] = mean;
        redQ[0][tid] = rsqrtf(var + 1e-5f);
    }
    __syncthreads();
#pragma unroll
    for (int m = 0; m < 2; ++m)
#pragma unroll
        for (int j = 0; j < 4; ++j) {
            const int ri = wm * 32 + m * 16 + lg * 4 + j;
            const long r = row0 + ri;
            if (r >= Mrows) continue;
            const float mean = redS[0][ri], rs = redQ[0][ri];
#pragma unroll
            for (int n = 0; n < 8; ++n) {
                const int c = wn * 128 + n * 16 + lr;
                const float o = (acc[m][n][j] - mean) * rs * g[c] + b[c];
                outf[r * DMODEL + c] = o;
                outb[r * DMODEL + c] = __float2bfloat16(o);
            }
        }
}

// ---------------------------------------------------------------------------
// 8-phase GEMM (round-8, refcheck'd). Used for FFN2 (K=2048).
// ---------------------------------------------------------------------------
template<int OUTMODE, bool GELU>
__global__ __launch_bounds__(512, 1)
void gemm8(const u16* __restrict__ A, int lda,
           const u16* __restrict__ Bt, int ldb,
           float* __restrict__ Cf, bf16* __restrict__ Cb, int ldc,
           const float* __restrict__ bias, const float* __restrict__ pos,
           int K, int rows_valid)
{
    __shared__ u16 Ash[2][2][256 * 32];
    __shared__ u16 Bsh[2][2][256 * 32];
    const int tid = threadIdx.x, wid = tid >> 6, lane = tid & 63;
    const int wm = wid >> 2, wn = wid & 3;
    const int lr = lane & 15, lg = lane >> 4;
    const u16* Ab = A + (long)blockIdx.y * 256 * lda;
    const u16* Bb = Bt + (long)blockIdx.x * 256 * ldb;
    const int srow = tid >> 2;
    const int soct = ((tid & 3) ^ (srow & 3)) * 8;
    const int slot8 = (lg ^ (lr & 3)) * 8;

    f32x4 acc[8][4] = {};

    auto stage = [&](u16* dst, const u16* src, int ld, int kt, int kh) {
#pragma unroll
        for (int i = 0; i < 2; ++i)
            __builtin_amdgcn_global_load_lds(
                (gas_ptr)(src + (long)(i * 128 + srow) * ld + kt * 64 + kh * 32 + soct),
                (las_ptr)(dst + (i * 512 + tid) * 8), 16, 0, 0);
    };

#define VMW(n) { asm volatile("s_waitcnt vmcnt(" #n ")" ::: "memory"); \
                 __builtin_amdgcn_sched_barrier(0); }
#define MFMA16(A0)                                                              \
    __builtin_amdgcn_s_setprio(1);                                             \
    _Pragma("unroll")                                                           \
    for (int m = 0; m < 4; ++m)                                                 \
        _Pragma("unroll")                                                       \
        for (int n = 0; n < 4; ++n)                                             \
            acc[(A0) + m][n] = __builtin_amdgcn_mfma_f32_16x16x32_bf16(         \
                af[m], bfr[n], acc[(A0) + m][n], 0, 0, 0);                      \
    __builtin_amdgcn_s_setprio(0);

    const int nt = K / 64;
    stage(&Ash[0][0][0], Ab, lda, 0, 0);
    stage(&Bsh[0][0][0], Bb, ldb, 0, 0);
    stage(&Ash[0][1][0], Ab, lda, 0, 1);
    stage(&Bsh[0][1][0], Bb, ldb, 0, 1);
    VMW(4);
    __builtin_amdgcn_s_barrier();

    for (int t = 0; t < nt; ++t) {
        const int db = t & 1;
        const bool nx = (t + 1 < nt);
        bf16x8 af[4], bfr[4];

#pragma unroll
        for (int n = 0; n < 4; ++n)
            bfr[n] = *(const bf16x8*)&Bsh[db][0][(wn * 64 + n * 16 + lr) * 32 + slot8];
#pragma unroll
        for (int m = 0; m < 4; ++m)
            af[m] = *(const bf16x8*)&Ash[db][0][(wm * 128 + m * 16 + lr) * 32 + slot8];
        if (nx) stage(&Ash[db ^ 1][0][0], Ab, lda, t + 1, 0);
        __builtin_amdgcn_s_barrier();
        MFMA16(0)
        __builtin_amdgcn_s_barrier();

#pragma unroll
        for (int m = 0; m < 4; ++m)
            af[m] = *(const bf16x8*)&Ash[db][0][(wm * 128 + 64 + m * 16 + lr) * 32 + slot8];
        if (nx) { stage(&Bsh[db ^ 1][0][0], Bb, ldb, t + 1, 0); VMW(4); }
        else    { VMW(0); }
        __builtin_amdgcn_s_barrier();
        MFMA16(4)
        __builtin_amdgcn_s_barrier();

#pragma unroll
        for (int n = 0; n < 4; ++n)
            bfr[n] = *(const bf16x8*)&Bsh[db][1][(wn * 64 + n * 16 + lr) * 32 + slot8];
#pragma unroll
        for (int m = 0; m < 4; ++m)
            af[m] = *(const bf16x8*)&Ash[db][1][(wm * 128 + m * 16 + lr) * 32 + slot8];
        if (nx) stage(&Ash[db ^ 1][1][0], Ab, lda, t + 1, 1);
        __builtin_amdgcn_s_barrier();
        MFMA16(0)
        __builtin_amdgcn_s_barrier();

#pragma unroll
        for (int m = 0; m < 4; ++m)
            af[m] = *(const bf16x8*)&Ash[db][1][(wm * 128 + 64 + m * 16 + lr) * 32 + slot8];
        if (nx) { stage(&Bsh[db ^ 1][1][0], Bb, ldb, t + 1, 1); VMW(4); }
        __builtin_amdgcn_s_barrier();
        MFMA16(4)
        __builtin_amdgcn_s_barrier();
    }
#undef MFMA16
#undef VMW

    const int cbase = blockIdx.x * 256 + wn * 64;
    const int rbase = blockIdx.y * 256 + wm * 128;
#pragma unroll
    for (int n = 0; n < 4; ++n) {
        const int c = cbase + n * 16 + lr;
        const float bval = bias ? bias[c] : 0.0f;
#pragma unroll
        for (int a = 0; a < 8; ++a) {
#pragma unroll
            for (int j = 0; j < 4; ++j) {
                const int r = rbase + a * 16 + lg * 4 + j;
                if (r >= rows_valid) continue;
                float v = acc[a][n][j] + bval;
                if constexpr (GELU) v = 0.5f * v * (1.0f + erff(v * 0.70710678118654752f));
                long idx;
                if constexpr (OUTMODE == 1) {
                    const int pb = r / 576, pt = r - pb * 576;
                    v += pos[(long)(1 + pt) * DMODEL + c];
                    idx = (long)(pb * TOKENS + 1 + pt) * ldc + c;
                } else {
                    idx = (long)r * ldc + c;
                }
                if (Cf) Cf[idx] = v;
                if (Cb) Cb[idx] = __float2bfloat16(v);
            }
        }
    }
}

// ---------------------------------------------------------------------------
// Fused flash attention (round-3 verified).
// ---------------------------------------------------------------------------
__global__ __launch_bounds__(256, 2)
void attn_flash(const u16* __restrict__ qkv, const u16* __restrict__ vhT,
                bf16* __restrict__ ob)
{
    __shared__ u16 ldsA[128 * 128];
    __shared__ u16 ldsB[128 * 128];
    const int tid = threadIdx.x;
    const int w = tid >> 6, lane = tid & 63;
    const int lr = lane & 15, lg = lane >> 4;
    const int pair = blockIdx.y;
    const int b = pair >> 2, h = pair & 3;
    const int q0 = blockIdx.x * 128;
    const long rowbase = (long)b * TOKENS;

    bf16x8 qf[2][4];
#pragma unroll
    for (int m = 0; m < 2; ++m)
#pragma unroll
        for (int kf = 0; kf < 4; ++kf) {
            const long r = rowbase + q0 + w * 32 + m * 16 + lr;
            qf[m][kf] = *(const bf16x8*)&qkv[r * 1536 + h * 128 + kf * 32 + lg * 8];
        }

    float mrun[2][4], lrun[2][4];
#pragma unroll
    for (int m = 0; m < 2; ++m)
#pragma unroll
        for (int j = 0; j < 4; ++j) { mrun[m][j] = -1e30f; lrun[m][j] = 0.f; }
    f32x4 oacc[2][8] = {};

    for (int kv0 = 0; kv0 < TPAD; kv0 += 128) {
        {
            const u16* kg = qkv + (rowbase + kv0) * 1536 + 512 + h * 128;
            const u16* vg = vhT + ((long)pair * 128) * TPAD + kv0;
#pragma unroll
            for (int p = 0; p < 8; ++p) {
                const int i = p * 16 + w * 4 + lg;
                __builtin_amdgcn_global_load_lds((gas_ptr)(kg + (long)i * 1536 + lr * 8),
                                                 (las_ptr)&ldsA[(p * 16 + w * 4) * 128], 16, 0, 0);
                __builtin_amdgcn_global_load_lds((gas_ptr)(vg + (long)i * TPAD + lr * 8),
                                                 (las_ptr)&ldsB[(p * 16 + w * 4) * 128], 16, 0, 0);
            }
        }
        __syncthreads();

        f32x4 s[2][8] = {};
#pragma unroll
        for (int kf = 0; kf < 4; ++kf) {
            bf16x8 bv[8];
#pragma unroll
            for (int n = 0; n < 8; ++n)
                bv[n] = *(const bf16x8*)&ldsA[(n * 16 + lr) * 128 + kf * 32 + lg * 8];
            __builtin_amdgcn_s_setprio(1);
#pragma unroll
            for (int m = 0; m < 2; ++m)
#pragma unroll
                for (int n = 0; n < 8; ++n)
                    s[m][n] = __builtin_amdgcn_mfma_f32_16x16x32_bf16(qf[m][kf], bv[n], s[m][n], 0, 0, 0);
            __builtin_amdgcn_s_setprio(0);
        }

        float sc[2][4];
#pragma unroll
        for (int m = 0; m < 2; ++m)
#pragma unroll
            for (int jj = 0; jj < 4; ++jj) {
                float mx = mrun[m][jj];
#pragma unroll
                for (int n = 0; n < 8; ++n) {
                    const int col = kv0 + n * 16 + lr;
                    float v = s[m][n][jj] * SM_SCALE;
                    v = (col < TOKENS) ? v : -1e30f;
                    s[m][n][jj] = v;
                    mx = fmaxf(mx, v);
                }
#pragma unroll
                for (int o = 1; o < 16; o <<= 1) mx = fmaxf(mx, __shfl_xor(mx, o));
                const float f = __expf(mrun[m][jj] - mx);
                sc[m][jj] = f;
                float sum = 0.f;
#pragma unroll
                for (int n = 0; n < 8; ++n) {
                    const float p = __expf(s[m][n][jj] - mx);
                    s[m][n][jj] = p;
                    sum += p;
                }
#pragma unroll
                for (int o = 1; o < 16; o <<= 1) sum += __shfl_xor(sum, o);
                lrun[m][jj] = lrun[m][jj] * f + sum;
                mrun[m][jj] = mx;
            }
#pragma unroll
        for (int m = 0; m < 2; ++m)
#pragma unroll
            for (int n = 0; n < 8; ++n)
#pragma unroll
                for (int jj = 0; jj < 4; ++jj) oacc[m][n][jj] *= sc[m][jj];

        __syncthreads();
#pragma unroll
        for (int m = 0; m < 2; ++m)
#pragma unroll
            for (int n = 0; n < 8; ++n)
#pragma unroll
                for (int jj = 0; jj < 4; ++jj)
                    ldsA[(w * 32 + m * 16 + lg * 4 + jj) * 128 + n * 16 + lr] = f2b(s[m][n][jj]);
        __syncthreads();

#pragma unroll
        for (int kf = 0; kf < 4; ++kf) {
            bf16x8 pa[2];
#pragma unroll
            for (int m = 0; m < 2; ++m)
                pa[m] = *(const bf16x8*)&ldsA[(w * 32 + m * 16 + lr) * 128 + kf * 32 + lg * 8];
            __builtin_amdgcn_s_setprio(1);
#pragma unroll
            for (int n = 0; n < 8; ++n) {
                const bf16x8 vb = *(const bf16x8*)&ldsB[(n * 16 + lr) * 128 + kf * 32 + lg * 8];
#pragma unroll
                for (int m = 0; m < 2; ++m)
                    oacc[m][n] = __builtin_amdgcn_mfma_f32_16x16x32_bf16(pa[m], vb, oacc[m][n], 0, 0, 0);
            }
            __builtin_amdgcn_s_setprio(0);
        }
        __syncthreads();
    }

#pragma unroll
    for (int m = 0; m < 2; ++m)
#pragma unroll
        for (int jj = 0; jj < 4; ++jj) {
            const float inv = 1.f / lrun[m][jj];
            const int q = q0 + w * 32 + m * 16 + lg * 4 + jj;
            if (q >= TOKENS) continue;
#pragma unroll
            for (int n = 0; n < 8; ++n)
                ob[(rowbase + q) * DMODEL + h * 128 + n * 16 + lr] =
                    __float2bfloat16(oacc[m][n][jj] * inv);
        }
}

// ---------------------------------------------------------------------------
// Patch-embed weight transpose (once): WT[n][k] = bf16(W[k][n])
// ---------------------------------------------------------------------------
__global__ __launch_bounds__(256)
void wtrans(const float* __restrict__ W, bf16* __restrict__ WT, int K, int N)
{
    __shared__ float tile[32][33];
    const int n0 = blockIdx.x * 32, k0 = blockIdx.y * 32;
    const int tx = threadIdx.x & 31, ty = threadIdx.x >> 5;
#pragma unroll
    for (int i = 0; i < 4; ++i)
        tile[ty + i * 8][tx] = W[(long)(k0 + ty + i * 8) * N + n0 + tx];
    __syncthreads();
#pragma unroll
    for (int i = 0; i < 4; ++i)
        WT[(long)(n0 + ty + i * 8) * K + k0 + tx] = __float2bfloat16(tile[tx][ty + i * 8]);
}

// ---------------------------------------------------------------------------
// Layer weight transpose: nl layers x 3072 tiles. Per layer offsets:
// wqkvT @0 (512x1536->perm), w0T @786432, w1T @1048576, w2T @2097152.
// ---------------------------------------------------------------------------
__global__ __launch_bounds__(256)
void wtrans_layers(const float* __restrict__ Wqkv, const float* __restrict__ W0,
                   const float* __restrict__ W1, const float* __restrict__ W2,
                   bf16* __restrict__ out, int layer0)
{
    const int bb = blockIdx.x;
    const int sl = bb / 3072;
    const int l = layer0 + sl;
    int t = bb % 3072;
    bf16* base = out + (long)sl * LAYER_W;
    const float* W; bf16* WT; int K, N; bool perm = false;
    if (t < 768)       {            W = Wqkv + (long)l * 512 * 1536; WT = base;           K = 512;  N = 1536; perm = true; }
    else if (t < 1024) { t -= 768;  W = W0   + (long)l * 512 * 512;  WT = base + 786432;  K = 512;  N = 512;  }
    else if (t < 2048) { t -= 1024; W = W1   + (long)l * 512 * 2048; WT = base + 1048576; K = 512;  N = 2048; }
    else               { t -= 2048; W = W2   + (long)l * 2048 * 512; WT = base + 2097152; K = 2048; N = 512;  }
    const int nx = N / 32;
    const int n0 = (t % nx) * 32, k0 = (t / nx) * 32;
    __shared__ float tile[32][33];
    const int tx = threadIdx.x & 31, ty = threadIdx.x >> 5;
#pragma unroll
    for (int i = 0; i < 4; ++i)
        tile[ty + i * 8][tx] = W[(long)(k0 + ty + i * 8) * N + n0 + tx];
    __syncthreads();
#pragma unroll
    for (int i = 0; i < 4; ++i) {
        int n = n0 + ty + i * 8;
        if (perm) {
            const int d = n / 12, rr = n % 12;
            n = (rr >> 2) * 512 + (rr & 3) * 128 + d;
        }
        WT[(long)n * K + k0 + tx] = __float2bfloat16(tile[tx][ty + i * 8]);
    }
}

// ---------------------------------------------------------------------------
__global__ __launch_bounds__(64)
void patch_gather(const float* __restrict__ img, bf16* __restrict__ pat)
{
    const int bid = blockIdx.x;
    const int x  = bid % 24;
    const int p1 = (bid / 24) % 16;
    const int b  = bid / (24 * 16);
    __shared__ bf16 lds[24][48];
    const int lane = threadIdx.x;
    const int h = p1 * 24 + x;
    for (int c = 0; c < 3; ++c) {
        const float* row = img + ((long)(b * 3 + c) * 384 + h) * 384;
#pragma unroll
        for (int i = 0; i < 6; ++i) {
            const int wpix = lane + i * 64;
            const float v = row[wpix];
            const int y = wpix % 24, p2 = wpix / 24;
            lds[y][p2 * 3 + c] = __float2bfloat16(v);
        }
    }
    __syncthreads();
    for (int idx = lane; idx < 24 * 48; idx += 64) {
        const int y = idx / 48, j = idx % 48;
        pat[(long)(b * 576 + x * 24 + y) * 768 + p1 * 48 + j] = lds[y][j];
    }
}

__global__ __launch_bounds__(256)
void clsfill(const float* __restrict__ cls, const float* __restrict__ pos,
             float* __restrict__ tokf, bf16* __restrict__ xb)
{
    const int i = blockIdx.x * 256 + threadIdx.x;
    const int b = i >> 9, d = i & 511;
    const float v = cls[d] + pos[d];
    tokf[(long)b * TOKENS * DMODEL + d] = v;
    xb[(long)b * TOKENS * DMODEL + d] = __float2bfloat16(v);
}

__global__ __launch_bounds__(256)
void repack_v(const u16* __restrict__ qkv, u16* __restrict__ vhT)
{
    __shared__ u16 lds[64][136];
    const int bid = blockIdx.x;
    const int tt = bid % 10, pair = bid / 10;
    const int b = pair >> 2, h = pair & 3;
    const int tid = threadIdx.x;
    const int tl = tid >> 2, seg = tid & 3;
    const long row = (long)b * TOKENS + tt * 64 + tl;
    const u16* src = qkv + row * 1536 + 1024 + h * 128 + seg * 32;
#pragma unroll
    for (int u = 0; u < 4; ++u)
        *(uint4*)&lds[tl][seg * 32 + u * 8] = *(const uint4*)&src[u * 8];
    __syncthreads();
    const int d = tid >> 1, th = (tid & 1) * 32;
    u16* dst = vhT + ((long)pair * 128 + d) * TPAD + tt * 64 + th;
#pragma unroll
    for (int blk = 0; blk < 4; ++blk) {
        uint4 pk; u16* pp = (u16*)&pk;
#pragma unroll
        for (int j = 0; j < 8; ++j) {
            const int t = tt * 64 + th + blk * 8 + j;
            pp[j] = (t < TOKENS) ? lds[th + blk * 8 + j][d] : (u16)0;
        }
        *(uint4*)&dst[blk * 8] = pk;
    }
}

// y = LN(xin + res)*g + b  (used for LN2 only)
__global__ __launch_bounds__(256)
void resln(const float* __restrict__ xin, const float* __restrict__ res,
           const float* __restrict__ g, const float* __restrict__ b,
           float* __restrict__ outf, bf16* __restrict__ outb, int nrows)
{
    const int row = blockIdx.x * 4 + (threadIdx.x >> 6);
    if (row >= nrows) return;
    const int lane = threadIdx.x & 63;
    const float* p1 = xin + (long)row * DMODEL;
    const float* p2 = res + (long)row * DMODEL;
    float v[8];
    float s = 0.f;
#pragma unroll
    for (int i = 0; i < 8; ++i) { v[i] = p1[lane + i * 64] + p2[lane + i * 64]; s += v[i]; }
#pragma unroll
    for (int o = 32; o; o >>= 1) s += __shfl_xor(s, o);
    const float mean = s * (1.f / 512.f);
    float q = 0.f;
#pragma unroll
    for (int i = 0; i < 8; ++i) { const float d = v[i] - mean; q += d * d; }
#pragma unroll
    for (int o = 32; o; o >>= 1) q += __shfl_xor(q, o);
    const float rs = rsqrtf(q * (1.f / 512.f) + 1e-5f);
#pragma unroll
    for (int i = 0; i < 8; ++i) {
        const int c = lane + i * 64;
        const float o = (v[i] - mean) * rs * g[c] + b[c];
        outf[(long)row * DMODEL + c] = o;
        outb[(long)row * DMODEL + c] = __float2bfloat16(o);
    }
}

__global__ __launch_bounds__(64)
void head_k(const float* __restrict__ tokf, const float* __restrict__ Wh,
            const float* __restrict__ bh, float* __restrict__ out)
{
    const int b = blockIdx.x;
    const int lane = threadIdx.x;
    const float* x = tokf + (long)b * TOKENS * DMODEL;
    float acc[10] = {};
#pragma unroll
    for (int i = 0; i < 8; ++i) {
        const int d = lane + i * 64;
        const float xv = x[d];
        const float* wr = Wh + (long)d * 10;
#pragma unroll
        for (int c = 0; c < 10; ++c) acc[c] += xv * wr[c];
    }
#pragma unroll
    for (int c = 0; c < 10; ++c)
#pragma unroll
        for (int o = 32; o; o >>= 1) acc[c] += __shfl_xor(acc[c], o);
    if (lane == 0) {
#pragma unroll
        for (int c = 0; c < 10; ++c) out[b * 10 + c] = acc[c] + bh[c];
    }
}

// ---------------------------------------------------------------------------
extern "C" void kernel_launch(void* const* d_in, const int* in_sizes, int n_in,
                              void* d_out, int out_size, void* d_ws, size_t ws_size,
                              hipStream_t stream)
{
    (void)in_sizes; (void)n_in; (void)out_size;
    const float* img    = (const float*)d_in[0];
    const float* Wpatch = (const float*)d_in[1];
    const float* bpatch = (const float*)d_in[2];
    const float* clstk  = (const float*)d_in[3];
    const float* pos    = (const float*)d_in[4];
    const float* Wqkv   = (const float*)d_in[5];
    const float* W0     = (const float*)d_in[6];
    const float* g1     = (const float*)d_in[7];
    const float* b1     = (const float*)d_in[8];
    const float* g2     = (const float*)d_in[9];
    const float* b2     = (const float*)d_in[10];
    const float* W1     = (const float*)d_in[11];
    const float* bb1    = (const float*)d_in[12];
    const float* W2     = (const float*)d_in[13];
    const float* bb2    = (const float*)d_in[14];
    const float* Whead  = (const float*)d_in[15];
    const float* bhead  = (const float*)d_in[16];

    // ---- config ladder: (batch chunk, weight buffers) ----
    static const int cand[7][2] = {{32,6},{32,1},{16,1},{8,1},{4,1},{2,1},{1,1}};
    int Bc = 0, nW = 1;
    size_t o_tokf=0, o_xb=0, o_R1=0, o_R2=0, o_ob=0, o_wp=0, o_wr=0;
    for (int ci = 0; ci < 7; ++ci) {
        const int bc = cand[ci][0], nw = cand[ci][1];
        const long Mrows = (long)bc * TOKENS;
        const long Mpad  = ((Mrows + 255) / 256) * 256;
        size_t off = 0;
        auto take = [&](size_t sz) { size_t o = off; off += (sz + 255) & ~(size_t)255; return o; };
        size_t t_tokf = take((size_t)Mpad * 512 * 4);
        size_t t_xb   = take((size_t)Mpad * 512 * 2);
        size_t t_R1   = take((size_t)Mpad * 2048 * 2);          // pat | qkv | h1b
        size_t r2a = (size_t)bc * 4 * TPAD * 128 * 2;           // vhT
        size_t r2b = (size_t)Mpad * 512 * 4;                    // t1 (f32)
        size_t t_R2 = take(r2a > r2b ? r2a : r2b);
        size_t t_ob   = take((size_t)Mpad * 512 * 2);
        size_t t_wp   = take((size_t)512 * 768 * 2);
        size_t t_wr   = take((size_t)nw * LAYER_W * 2);
        if (off <= ws_size) {
            Bc = bc; nW = nw;
            o_tokf=t_tokf; o_xb=t_xb; o_R1=t_R1; o_R2=t_R2; o_ob=t_ob; o_wp=t_wp; o_wr=t_wr;
            break;
        }
    }
    if (Bc == 0) return;

    const long Mrows = (long)Bc * TOKENS;
    const long Mpad  = ((Mrows + 255) / 256) * 256;
    const int  NP    = Bc * 4;
    const int  gy128 = (int)(Mpad / 128);
    const int  gy256 = (int)(Mpad / 256);
    const int  nproj = (int)((Mrows + 63) / 64);
    const long patRows = ((long)Bc * 576 + 127) / 128 * 128;

    char* base = (char*)d_ws;
    float* tokf = (float*)(base + o_tokf);
    bf16*  xb   = (bf16*)(base + o_xb);
    char*  R1   = base + o_R1;
    char*  R2   = base + o_R2;
    bf16*  ob   = (bf16*)(base + o_ob);
    bf16*  wpT  = (bf16*)(base + o_wp);
    bf16*  wAll = (bf16*)(base + o_wr);

    u16*  qkvb = (u16*)R1;
    bf16* pat  = (bf16*)R1;
    u16*  h1b  = (u16*)R1;
    u16*  vhT  = (u16*)R2;
    float* t1  = (float*)R2;

    wtrans<<<dim3(512 / 32, 768 / 32), 256, 0, stream>>>(Wpatch, wpT, 768, 512);
    if (nW == 6)
        wtrans_layers<<<6 * 3072, 256, 0, stream>>>(Wqkv, W0, W1, W2, wAll, 0);

    const int nchunks = 32 / Bc;
    for (int ch = 0; ch < nchunks; ++ch) {
        const float* img_c = img + (long)ch * Bc * 3 * 384 * 384;

        hipMemsetAsync(xb, 0, (size_t)Mpad * 512 * 2, stream);   // pad rows -> exact 0
        clsfill<<<Bc * 2, 256, 0, stream>>>(clstk, pos, tokf, xb);
        patch_gather<<<Bc * 16 * 24, 64, 0, stream>>>(img_c, pat);
        gemm_bt<1, false><<<dim3(4, (int)(patRows / 128)), 256, 0, stream>>>(
            (const u16*)pat, 768, (const u16*)wpT, 768,
            tokf, xb, 512, bpatch, pos, 768, Bc * 576);

        for (int l = 0; l < 6; ++l) {
            const bf16* wL = wAll + (nW == 6 ? (long)l * LAYER_W : 0);
            if (nW == 1)
                wtrans_layers<<<3072, 256, 0, stream>>>(Wqkv, W0, W1, W2, wAll, l);
            const u16* wqkvT = (const u16*)wL;
            const u16* w0T   = (const u16*)(wL + 786432);
            const u16* w1T   = (const u16*)(wL + 1048576);
            const u16* w2T   = (const u16*)(wL + 2097152);

            // qkv = x @ Wqkv  (permuted cols: kk*512 + h*128 + d)
            gemm_bt<0, false><<<dim3(12, gy128), 256, 0, stream>>>(
                (const u16*)xb, 512, wqkvT, 512,
                nullptr, (bf16*)qkvb, 1536, nullptr, nullptr, 512, (int)Mpad);

            repack_v<<<NP * 10, 256, 0, stream>>>(qkvb, vhT);
            attn_flash<<<dim3(5, NP), 256, 0, stream>>>(qkvb, vhT, ob);

            // fused proj + residual + LN1 -> tokf, xb
            proj_ln<<<nproj, 512, 0, stream>>>(
                (const u16*)ob, w0T, tokf, g1 + l * 512, b1 + l * 512,
                tokf, xb, (int)Mrows);

            // h1 = gelu(y @ W1 + bb1)  (BK=32 swizzled; h1b overwrites qkv)
            gemm_bt32<true><<<dim3(16, gy128), 256, 0, stream>>>(
                (const u16*)xb, 512, w1T, 512,
                (bf16*)h1b, 2048, bb1 + l * 2048, 512, (int)Mrows);

            // t1 = h1 @ W2 + bb2  (K=2048 -> 8-phase pipeline)
            gemm8<0, false><<<dim3(2, gy256), 512, 0, stream>>>(
                (const u16*)h1b, 2048, w2T, 2048,
                t1, nullptr, 512, bb2 + l * 512, nullptr, 2048, (int)Mrows);
            // x = LN(t1 + y) -> tokf, xb
            resln<<<(int)((Mrows + 3) / 4), 256, 0, stream>>>(
                t1, tokf, g2 + l * 512, b2 + l * 512, tokf, xb, (int)Mrows);
        }

        head_k<<<Bc, 64, 0, stream>>>(tokf, Whead, bhead, (float*)d_out + (long)ch * Bc * 10);
    }
}